// Round 9
// baseline (626.267 us; speedup 1.0000x reference)
//
#include <hip/hip_runtime.h>
#include <hip/hip_bf16.h>

#define EPSV 1e-5f

using s8v = __attribute__((ext_vector_type(8))) short;
using f4v = __attribute__((ext_vector_type(4))) float;

__device__ __forceinline__ float bf2f(ushort u){
  union { unsigned int i; float f; } x; x.i = ((unsigned int)u)<<16; return x.f;
}
__device__ __forceinline__ ushort f2bf(float f){
  union { float f; unsigned int i; } x; x.f = f;
  unsigned int r = x.i + 0x7FFFu + ((x.i>>16)&1u);
  return (ushort)(r>>16);
}

__device__ __forceinline__ void gload16(const void* g, void* l){
  __builtin_amdgcn_global_load_lds((__attribute__((address_space(1))) void*)g,
                                   (__attribute__((address_space(3))) void*)l, 16, 0, 0);
}

// ---------------- input repack: NCHW f32 (x1|x2) -> padded NHWC bf16 [8][66][66][256] ----------------
__global__ __launch_bounds__(256) void repack_in_k(const float* __restrict__ x1,
                                                   const float* __restrict__ x2,
                                                   ushort* __restrict__ Xin){
  __shared__ ushort tile[256][66];
  const int y = blockIdx.x, b = blockIdx.y, tid = threadIdx.x;
  const int xl = tid & 63, cq = tid >> 6;
  for (int it=0; it<64; it++){
    int ci = it*4 + cq;
    float v;
    if (ci < 128) v = x1[(((long)b*128 + ci)*64 + y)*64 + xl];
    else          v = x2[(((long)b*128 + (ci-128))*64 + y)*64 + xl];
    tile[ci][xl] = f2bf(v);
  }
  __syncthreads();
  for (int x=0; x<64; x++){
    Xin[(((long)b*66 + (y+1))*66 + (x+1))*256 + tid] = tile[tid][x];
  }
}

// ---------------- conv weight repack: Wc[co][dd*256+ci] = w[co][ci][dd] ----------------
__global__ void repack_convw_k(const float* __restrict__ w, ushort* __restrict__ Wc){
  const long total = 256L*2304;
  for (long e = (long)blockIdx.x*blockDim.x + threadIdx.x; e < total; e += (long)gridDim.x*blockDim.x){
    int co = (int)(e / 2304), kk = (int)(e % 2304);
    int dd = kk >> 8, ci = kk & 255;
    Wc[e] = f2bf(w[((long)(co*256 + ci))*9 + dd]);
  }
}

// ---------------- weight transpose f32[K][N] -> bf16[N][K] ----------------
__global__ void transpose_w_k(const float* __restrict__ src, ushort* __restrict__ dst, int K, int N){
  long total = (long)K*N;
  for (long e = (long)blockIdx.x*blockDim.x + threadIdx.x; e < total; e += (long)gridDim.x*blockDim.x){
    int k = (int)(e / N), n = (int)(e % N);
    dst[(long)n*K + k] = f2bf(src[e]);
  }
}

__global__ void bnprep_k(const float* cb, const float* g, const float* b,
                         const float* m, const float* v, float* sc, float* sh){
  int n = threadIdx.x;
  if (n < 256){
    float s = g[n] * rsqrtf(v[n] + EPSV);
    sc[n] = s;
    sh[n] = (cb[n] - m[n])*s + b[n];
  }
}

// ---------------- MFMA GEMM: C = A[M][K] @ Wt[N][K]^T ----------------
// EPI: 0 bf16 store; 1 bf16 bias+GELU; 2 f32 resid += v+bias; 3 f32 conv-BN (v*sc+sh)
#define BM 128
#define BN 128
#define BK 64
template<int EPI, bool CONVA>
__global__ __launch_bounds__(256) void gemm_k(
    const ushort* __restrict__ A, const ushort* __restrict__ Xin,
    const ushort* __restrict__ Wt, const float* __restrict__ bias,
    const float* __restrict__ sc, const float* __restrict__ sh,
    float* __restrict__ resid, ushort* __restrict__ outb, float* __restrict__ outf,
    int N, int K)
{
  __shared__ ushort As[BM*BK];
  __shared__ ushort Bs[BN*BK];
  const int tid = threadIdx.x, wid = tid>>6, lane = tid&63;
  const int m0 = blockIdx.x*BM, n0 = blockIdx.y*BN;
  const int wm = (wid>>1)*64, wn = (wid&1)*64;
  const int l15 = lane&15, lg = lane>>4;

  const int rA = wid*32 + (lane>>3);
  const int cA = (lane&7)*8;
  const ushort* pA[4];
  if (CONVA){
    #pragma unroll
    for (int j=0;j<4;j++){
      int t = m0 + rA + j*8;
      int b = t>>12, y = (t>>6)&63, x = t&63;
      pA[j] = Xin + ((long)((b*66 + y+1)*66) + (x+1))*256 + cA;
    }
  } else {
    #pragma unroll
    for (int j=0;j<4;j++) pA[j] = A + (long)(m0 + rA + j*8)*K + cA;
  }
  const ushort* pB[4];
  #pragma unroll
  for (int j=0;j<4;j++) pB[j] = Wt + (long)(n0 + rA + j*8)*K + cA;

  f4v acc[4][4] = {};

  for (int k0=0; k0<K; k0+=BK){
    int koffA;
    if (CONVA){
      int dd = k0 >> 8;
      int dy = dd/3, dx = dd - dy*3;
      koffA = ((dy-1)*66 + (dx-1))*256 + (k0 & 255);
    } else koffA = k0;
    #pragma unroll
    for (int j=0;j<4;j++){
      gload16(pA[j] + koffA, (void*)&As[(wid*32 + j*8)*BK]);
      gload16(pB[j] + k0,   (void*)&Bs[(wid*32 + j*8)*BK]);
    }
    __syncthreads();
    #pragma unroll
    for (int kk=0; kk<2; kk++){
      s8v a[4], b[4];
      const int ke = kk*32 + lg*8;
      #pragma unroll
      for (int mi=0;mi<4;mi++) a[mi] = *(const s8v*)&As[(wm + mi*16 + l15)*BK + ke];
      #pragma unroll
      for (int ni=0;ni<4;ni++) b[ni] = *(const s8v*)&Bs[(wn + ni*16 + l15)*BK + ke];
      #pragma unroll
      for (int mi=0;mi<4;mi++)
        #pragma unroll
        for (int ni=0;ni<4;ni++)
          acc[mi][ni] = __builtin_amdgcn_mfma_f32_16x16x32_bf16(a[mi], b[ni], acc[mi][ni], 0,0,0);
    }
    __syncthreads();
  }

  #pragma unroll
  for (int mi=0;mi<4;mi++)
    #pragma unroll
    for (int ni=0;ni<4;ni++)
      #pragma unroll
      for (int r=0;r<4;r++){
        int gm = m0 + wm + mi*16 + lg*4 + r;
        int gn = n0 + wn + ni*16 + l15;
        float v = acc[mi][ni][r];
        if (EPI==0){
          outb[(long)gm*N + gn] = f2bf(v);
        } else if (EPI==1){
          v += bias[gn];
          v = 0.5f*v*(1.0f + erff(v*0.70710678118654752f));
          outb[(long)gm*N + gn] = f2bf(v);
        } else if (EPI==2){
          resid[(long)gm*N + gn] += v + bias[gn];
        } else {
          outf[(long)gm*N + gn] = v*sc[gn] + sh[gn];
        }
      }
}

// ---------------- LayerNorm over C=256 ----------------
__global__ __launch_bounds__(256) void ln_k(const float* __restrict__ X,
    const float* __restrict__ g, const float* __restrict__ b,
    float* __restrict__ outf, ushort* __restrict__ outb)
{
  const int wid = threadIdx.x>>6, lane = threadIdx.x&63;
  const long row = (long)blockIdx.x*4 + wid;
  const float4 v = *(const float4*)&X[row*256 + lane*4];
  float s = v.x+v.y+v.z+v.w;
  #pragma unroll
  for (int m=1;m<64;m<<=1) s += __shfl_xor(s, m);
  float mu = s * (1.0f/256.0f);
  float d0=v.x-mu, d1=v.y-mu, d2=v.z-mu, d3=v.w-mu;
  float q = d0*d0+d1*d1+d2*d2+d3*d3;
  #pragma unroll
  for (int m=1;m<64;m<<=1) q += __shfl_xor(q, m);
  float rs = rsqrtf(q*(1.0f/256.0f) + EPSV);
  int c = lane*4;
  float o0 = d0*rs*g[c+0] + b[c+0];
  float o1 = d1*rs*g[c+1] + b[c+1];
  float o2 = d2*rs*g[c+2] + b[c+2];
  float o3 = d3*rs*g[c+3] + b[c+3];
  if (outf){ float4 o = {o0,o1,o2,o3}; *(float4*)&outf[row*256 + c] = o; }
  if (outb){
    ushort4 u; u.x=f2bf(o0); u.y=f2bf(o1); u.z=f2bf(o2); u.w=f2bf(o3);
    *(ushort4*)&outb[row*256 + c] = u;
  }
}

// ---------------- stripe-window attention + LePE ----------------
__global__ __launch_bounds__(256) void attn_k(
    const ushort* __restrict__ QKV, ushort* __restrict__ ATT,
    const float* __restrict__ lepe_w, const float* __restrict__ lepe_b, int layer)
{
  __shared__ ushort q_lds[128][40];
  __shared__ ushort k_lds[128][40];
  __shared__ ushort vT[32][136];
  __shared__ ushort P[128][136];
  __shared__ float wl[32][9];
  __shared__ float bl[32];
  const int tid = threadIdx.x, wid = tid>>6, lane = tid&63;
  const int br = blockIdx.z, b = blockIdx.y;
  const int w = blockIdx.x>>2, h = blockIdx.x&3;
  const int choff = br*128 + h*32;
  const int l15 = lane&15, lg = lane>>4;

  auto tokf = [&](int s)->long{
    int y, x;
    if (br==0){ y = s>>1; x = (w<<1)|(s&1); }
    else      { y = (w<<1)|(s>>6); x = s&63; }
    return (long)((((b<<6)+y)<<6) + x);
  };

  for (int e = tid; e < 1536; e += 256){
    int tile = e>>9, rr = (e>>2)&127, c16 = (e&3)*8;
    long srcoff = tokf(rr)*768 + tile*256 + choff + c16;
    uint4 val = *(const uint4*)&QKV[srcoff];
    if (tile==0)      *(uint4*)&q_lds[rr][c16] = val;
    else if (tile==1) *(uint4*)&k_lds[rr][c16] = val;
    else {
      const ushort* u = (const ushort*)&val;
      #pragma unroll
      for (int jj=0;jj<8;jj++) vT[c16+jj][rr] = u[jj];
    }
  }
  for (int e = tid; e < 288; e += 256){
    int d = e/9, tap = e%9;
    wl[d][tap] = lepe_w[((long)((layer*2+br)*128 + h*32 + d))*9 + tap];
  }
  if (tid < 32) bl[tid] = lepe_b[(layer*2+br)*128 + h*32 + tid];
  __syncthreads();

  const int wrow = wid*32;
  f4v accS[2][8];
  {
    s8v aq[2];
    #pragma unroll
    for (int mi=0;mi<2;mi++) aq[mi] = *(const s8v*)&q_lds[wrow + mi*16 + l15][lg*8];
    #pragma unroll
    for (int ni=0;ni<8;ni++){
      s8v bk = *(const s8v*)&k_lds[ni*16 + l15][lg*8];
      #pragma unroll
      for (int mi=0;mi<2;mi++){
        f4v z = {0.f,0.f,0.f,0.f};
        accS[mi][ni] = __builtin_amdgcn_mfma_f32_16x16x32_bf16(aq[mi], bk, z, 0,0,0);
      }
    }
  }
  const float scale = 0.17677669529663689f;
  #pragma unroll
  for (int mi=0;mi<2;mi++){
    #pragma unroll
    for (int r=0;r<4;r++){
      float vals[8]; float mx = -1e30f;
      #pragma unroll
      for (int ni=0;ni<8;ni++){ vals[ni] = accS[mi][ni][r]*scale; mx = fmaxf(mx, vals[ni]); }
      #pragma unroll
      for (int msk=1; msk<16; msk<<=1) mx = fmaxf(mx, __shfl_xor(mx, msk));
      float ssum = 0.f;
      #pragma unroll
      for (int ni=0;ni<8;ni++){ vals[ni] = __expf(vals[ni]-mx); ssum += vals[ni]; }
      #pragma unroll
      for (int msk=1; msk<16; msk<<=1) ssum += __shfl_xor(ssum, msk);
      float inv = 1.0f/ssum;
      int s = wrow + mi*16 + lg*4 + r;
      #pragma unroll
      for (int ni=0;ni<8;ni++) P[s][ni*16+l15] = f2bf(vals[ni]*inv);
    }
  }
  __syncthreads();
  f4v acc2[2][2] = {};
  #pragma unroll
  for (int ks=0;ks<4;ks++){
    int kt = ks*32 + lg*8;
    s8v ap[2], bv[2];
    #pragma unroll
    for (int mi=0;mi<2;mi++) ap[mi] = *(const s8v*)&P[wrow + mi*16 + l15][kt];
    #pragma unroll
    for (int di=0;di<2;di++) bv[di] = *(const s8v*)&vT[di*16 + l15][kt];
    #pragma unroll
    for (int mi=0;mi<2;mi++)
      #pragma unroll
      for (int di=0;di<2;di++)
        acc2[mi][di] = __builtin_amdgcn_mfma_f32_16x16x32_bf16(ap[mi], bv[di], acc2[mi][di], 0,0,0);
  }
  #pragma unroll
  for (int mi=0;mi<2;mi++)
    #pragma unroll
    for (int di=0;di<2;di++)
      #pragma unroll
      for (int r=0;r<4;r++){
        int s = wrow + mi*16 + lg*4 + r;
        int d = di*16 + l15;
        float v = acc2[mi][di][r] + bl[d];
        int hs, ws2, HsL, WsL;
        if (br==0){ hs = s>>1; ws2 = s&1;  HsL = 64; WsL = 2; }
        else      { hs = s>>6; ws2 = s&63; HsL = 2;  WsL = 64; }
        #pragma unroll
        for (int a=-1;a<=1;a++)
          #pragma unroll
          for (int bb=-1;bb<=1;bb++){
            int h2 = hs+a, w2 = ws2+bb;
            if (h2>=0 && h2<HsL && w2>=0 && w2<WsL){
              int s2 = h2*WsL + w2;
              v += wl[d][(a+1)*3 + (bb+1)] * bf2f(vT[d][s2]);
            }
          }
        ATT[tokf(s)*256 + choff + d] = f2bf(v);
      }
}

// ---------------- final write: T [M][256] f32 -> d_out FLOAT32 (two NCHW halves) ----------------
// out flat = half*4194304 + b*524288 + c*4096 + l ; value = T[(b*4096+l)*256 + half*128 + c]
__global__ __launch_bounds__(256) void write_out_k(const float* __restrict__ T, float* __restrict__ out){
  const long idx = (long)blockIdx.x*256 + threadIdx.x;
  const int half = (int)(idx >> 22);
  const long rem = idx & 4194303L;
  const int b = (int)(rem >> 19);
  const int c = (int)((rem >> 12) & 127);
  const int l = (int)(rem & 4095);
  out[idx] = T[((long)b*4096 + l)*256 + half*128 + c];
}

extern "C" void kernel_launch(void* const* d_in, const int* in_sizes, int n_in,
                              void* d_out, int out_size, void* d_ws, size_t ws_size,
                              hipStream_t stream)
{
  (void)in_sizes; (void)n_in; (void)out_size;
  const float* x1     = (const float*)d_in[0];
  const float* x2     = (const float*)d_in[1];
  const float* conv_w = (const float*)d_in[2];
  const float* conv_b = (const float*)d_in[3];
  const float* bn_g   = (const float*)d_in[4];
  const float* bn_b   = (const float*)d_in[5];
  const float* bn_m   = (const float*)d_in[6];
  const float* bn_v   = (const float*)d_in[7];
  const float* ln0_g  = (const float*)d_in[8];
  const float* ln0_b  = (const float*)d_in[9];
  const float* n1_g   = (const float*)d_in[10];
  const float* n1_b   = (const float*)d_in[11];
  const float* qkv_w  = (const float*)d_in[12];
  const float* lepe_w = (const float*)d_in[13];
  const float* lepe_b = (const float*)d_in[14];
  const float* proj_w = (const float*)d_in[15];
  const float* proj_b = (const float*)d_in[16];
  const float* n2_g   = (const float*)d_in[17];
  const float* n2_b   = (const float*)d_in[18];
  const float* fc1_w  = (const float*)d_in[19];
  const float* fc1_b  = (const float*)d_in[20];
  const float* fc2_w  = (const float*)d_in[21];
  const float* fc2_b  = (const float*)d_in[22];

  if (ws_size < 121767936ULL){
    hipMemsetAsync(d_out, 0, (size_t)out_size*4, stream);
    return;
  }

  char* ws = (char*)d_ws;
  // R1 (64MB): QKVb(50.3MB)/H1b(64MB... uses 67.1? no: 32768*1024*2=67.1MB) — give R1 67.1MB
  ushort* QKVb = (ushort*)ws;
  ushort* H1b  = (ushort*)ws;
  float*  TMPf = (float*)ws;           // conv output f32 (33.5MB), dead before QKVb/H1b used
  size_t off = 67108864;
  float*  T    = (float*)(ws + off);   // f32 residual stream (33.5MB)
  ushort* Xin  = (ushort*)(ws + off);  // padded conv input (17.8MB) — dead before T written
  off += 33554432;
  ushort* Xb   = (ushort*)(ws + off);
  ushort* ATTb = (ushort*)(ws + off);  // alias: lifetimes interleave, never overlap
  off += 16777216;
  ushort* Wc   = (ushort*)(ws + off); off += 1179648;
  ushort* Wq   = (ushort*)(ws + off); off += 786432;
  ushort* Wp   = (ushort*)(ws + off); off += 262144;
  ushort* W1   = (ushort*)(ws + off); off += 1048576;
  ushort* W2   = (ushort*)(ws + off); off += 1048576;
  float*  scv  = (float*)(ws + off);  off += 1024;
  float*  shv  = (float*)(ws + off);  off += 1024;

  hipMemsetAsync(Xin, 0, (size_t)8*66*66*256*2, stream);
  repack_in_k<<<dim3(64,8), 256, 0, stream>>>(x1, x2, Xin);
  repack_convw_k<<<576, 256, 0, stream>>>(conv_w, Wc);
  for (int i=0;i<2;i++){
    transpose_w_k<<<512,256,0,stream>>>(qkv_w + (long)i*196608, Wq + (long)i*196608, 256, 768);
    transpose_w_k<<<128,256,0,stream>>>(proj_w + (long)i*65536, Wp + (long)i*65536, 256, 256);
    transpose_w_k<<<512,256,0,stream>>>(fc1_w + (long)i*262144, W1 + (long)i*262144, 256, 1024);
    transpose_w_k<<<512,256,0,stream>>>(fc2_w + (long)i*262144, W2 + (long)i*262144, 1024, 256);
  }
  bnprep_k<<<1,256,0,stream>>>(conv_b, bn_g, bn_b, bn_m, bn_v, scv, shv);

  // conv 3x3 + BN (implicit GEMM, K=2304) -> TMPf f32
  gemm_k<3,true><<<dim3(256,2),256,0,stream>>>(nullptr, Xin, Wc, nullptr, scv, shv,
                                               nullptr, nullptr, TMPf, 256, 2304);
  // LN0 -> T (f32 residual stream; overwrites Xin alias after Xin is dead)
  ln_k<<<8192,256,0,stream>>>(TMPf, ln0_g, ln0_b, T, nullptr);

  for (int i=0;i<2;i++){
    ln_k<<<8192,256,0,stream>>>(T, n1_g + i*256, n1_b + i*256, nullptr, Xb);
    gemm_k<0,false><<<dim3(256,6),256,0,stream>>>(Xb, nullptr, Wq + (long)i*196608, nullptr,
                                                  nullptr, nullptr, nullptr, QKVb, nullptr, 768, 256);
    attn_k<<<dim3(128,8,2),256,0,stream>>>(QKVb, ATTb, lepe_w, lepe_b, i);
    gemm_k<2,false><<<dim3(256,2),256,0,stream>>>(ATTb, nullptr, Wp + (long)i*65536, proj_b + i*256,
                                                  nullptr, nullptr, T, nullptr, nullptr, 256, 256);
    ln_k<<<8192,256,0,stream>>>(T, n2_g + i*256, n2_b + i*256, nullptr, Xb);
    gemm_k<1,false><<<dim3(256,8),256,0,stream>>>(Xb, nullptr, W1 + (long)i*262144, fc1_b + i*1024,
                                                  nullptr, nullptr, nullptr, H1b, nullptr, 1024, 256);
    gemm_k<2,false><<<dim3(256,2),256,0,stream>>>(H1b, nullptr, W2 + (long)i*262144, fc2_b + i*256,
                                                  nullptr, nullptr, T, nullptr, nullptr, 256, 1024);
  }
  write_out_k<<<32768,256,0,stream>>>(T, (float*)d_out);
}

// Round 10
// 589.319 us; speedup vs baseline: 1.0627x; 1.0627x over previous
//
#include <hip/hip_runtime.h>
#include <hip/hip_bf16.h>

#define EPSV 1e-5f

using s8v = __attribute__((ext_vector_type(8))) short;
using f4v = __attribute__((ext_vector_type(4))) float;

__device__ __forceinline__ float bf2f(ushort u){
  union { unsigned int i; float f; } x; x.i = ((unsigned int)u)<<16; return x.f;
}
__device__ __forceinline__ ushort f2bf(float f){
  union { float f; unsigned int i; } x; x.f = f;
  unsigned int r = x.i + 0x7FFFu + ((x.i>>16)&1u);
  return (ushort)(r>>16);
}

__device__ __forceinline__ void gload16(const void* g, void* l){
  __builtin_amdgcn_global_load_lds((__attribute__((address_space(1))) void*)g,
                                   (__attribute__((address_space(3))) void*)l, 16, 0, 0);
}

// ---------------- input repack: NCHW f32 (x1|x2) -> padded NHWC bf16 [8][66][66][256] ----------------
__global__ __launch_bounds__(256) void repack_in_k(const float* __restrict__ x1,
                                                   const float* __restrict__ x2,
                                                   ushort* __restrict__ Xin){
  __shared__ ushort tile[256][66];
  const int y = blockIdx.x, b = blockIdx.y, tid = threadIdx.x;
  const int xl = tid & 63, cq = tid >> 6;
  for (int it=0; it<64; it++){
    int ci = it*4 + cq;
    float v;
    if (ci < 128) v = x1[(((long)b*128 + ci)*64 + y)*64 + xl];
    else          v = x2[(((long)b*128 + (ci-128))*64 + y)*64 + xl];
    tile[ci][xl] = f2bf(v);
  }
  __syncthreads();
  for (int x=0; x<64; x++){
    Xin[(((long)b*66 + (y+1))*66 + (x+1))*256 + tid] = tile[tid][x];
  }
}

// ---------------- conv weight repack: Wc[co][dd*256+ci] = w[co][ci][dd] ----------------
__global__ void repack_convw_k(const float* __restrict__ w, ushort* __restrict__ Wc){
  const long total = 256L*2304;
  for (long e = (long)blockIdx.x*blockDim.x + threadIdx.x; e < total; e += (long)gridDim.x*blockDim.x){
    int co = (int)(e / 2304), kk = (int)(e % 2304);
    int dd = kk >> 8, ci = kk & 255;
    Wc[e] = f2bf(w[((long)(co*256 + ci))*9 + dd]);
  }
}

// ---------------- weight transpose f32[K][N] -> bf16[N][K] ----------------
__global__ void transpose_w_k(const float* __restrict__ src, ushort* __restrict__ dst, int K, int N){
  long total = (long)K*N;
  for (long e = (long)blockIdx.x*blockDim.x + threadIdx.x; e < total; e += (long)gridDim.x*blockDim.x){
    int k = (int)(e / N), n = (int)(e % N);
    dst[(long)n*K + k] = f2bf(src[e]);
  }
}

__global__ void bnprep_k(const float* cb, const float* g, const float* b,
                         const float* m, const float* v, float* sc, float* sh){
  int n = threadIdx.x;
  if (n < 256){
    float s = g[n] * rsqrtf(v[n] + EPSV);
    sc[n] = s;
    sh[n] = (cb[n] - m[n])*s + b[n];
  }
}

// ---------------- MFMA GEMM: C = A[M][K] @ Wt[N][K]^T ----------------
// EPI: 0 bf16 store; 1 bf16 bias+GELU; 2 f32 resid += v+bias; 3 f32 conv-BN; 4 qkv window-permuted bf16
#define BM 128
#define BN 128
#define BK 64
template<int EPI, bool CONVA>
__global__ __launch_bounds__(256) void gemm_k(
    const ushort* __restrict__ A, const ushort* __restrict__ Xin,
    const ushort* __restrict__ Wt, const float* __restrict__ bias,
    const float* __restrict__ sc, const float* __restrict__ sh,
    float* __restrict__ resid, ushort* __restrict__ outb, float* __restrict__ outf,
    int N, int K)
{
  __shared__ ushort As[BM*BK];
  __shared__ ushort Bs[BN*BK];
  const int tid = threadIdx.x, wid = tid>>6, lane = tid&63;
  const int m0 = blockIdx.x*BM, n0 = blockIdx.y*BN;
  const int wm = (wid>>1)*64, wn = (wid&1)*64;
  const int l15 = lane&15, lg = lane>>4;

  const int rA = wid*32 + (lane>>3);
  const int cA = (lane&7)*8;
  const ushort* pA[4];
  if (CONVA){
    #pragma unroll
    for (int j=0;j<4;j++){
      int t = m0 + rA + j*8;
      int b = t>>12, y = (t>>6)&63, x = t&63;
      pA[j] = Xin + ((long)((b*66 + y+1)*66) + (x+1))*256 + cA;
    }
  } else {
    #pragma unroll
    for (int j=0;j<4;j++) pA[j] = A + (long)(m0 + rA + j*8)*K + cA;
  }
  const ushort* pB[4];
  #pragma unroll
  for (int j=0;j<4;j++) pB[j] = Wt + (long)(n0 + rA + j*8)*K + cA;

  f4v acc[4][4] = {};

  for (int k0=0; k0<K; k0+=BK){
    int koffA;
    if (CONVA){
      int dd = k0 >> 8;
      int dy = dd/3, dx = dd - dy*3;
      koffA = ((dy-1)*66 + (dx-1))*256 + (k0 & 255);
    } else koffA = k0;
    #pragma unroll
    for (int j=0;j<4;j++){
      gload16(pA[j] + koffA, (void*)&As[(wid*32 + j*8)*BK]);
      gload16(pB[j] + k0,   (void*)&Bs[(wid*32 + j*8)*BK]);
    }
    __syncthreads();
    #pragma unroll
    for (int kk=0; kk<2; kk++){
      s8v a[4], b[4];
      const int ke = kk*32 + lg*8;
      #pragma unroll
      for (int mi=0;mi<4;mi++) a[mi] = *(const s8v*)&As[(wm + mi*16 + l15)*BK + ke];
      #pragma unroll
      for (int ni=0;ni<4;ni++) b[ni] = *(const s8v*)&Bs[(wn + ni*16 + l15)*BK + ke];
      #pragma unroll
      for (int mi=0;mi<4;mi++)
        #pragma unroll
        for (int ni=0;ni<4;ni++)
          acc[mi][ni] = __builtin_amdgcn_mfma_f32_16x16x32_bf16(a[mi], b[ni], acc[mi][ni], 0,0,0);
    }
    __syncthreads();
  }

  #pragma unroll
  for (int mi=0;mi<4;mi++)
    #pragma unroll
    for (int ni=0;ni<4;ni++)
      #pragma unroll
      for (int r=0;r<4;r++){
        int gm = m0 + wm + mi*16 + lg*4 + r;
        int gn = n0 + wn + ni*16 + l15;
        float v = acc[mi][ni][r];
        if (EPI==0){
          outb[(long)gm*N + gn] = f2bf(v);
        } else if (EPI==1){
          v += bias[gn];
          v = 0.5f*v*(1.0f + erff(v*0.70710678118654752f));
          outb[(long)gm*N + gn] = f2bf(v);
        } else if (EPI==2){
          resid[(long)gm*N + gn] += v + bias[gn];
        } else if (EPI==3){
          outf[(long)gm*N + gn] = v*sc[gn] + sh[gn];
        } else {
          // EPI==4: window-ordered QKV store: [tile(3)][br(2)][head(4)][(b*32+w)*128+s][32]
          int tile = gn >> 8;
          int c = gn & 255;
          int br2 = (c >> 7) & 1;
          int hh = (c >> 5) & 3;
          int d = c & 31;
          int bb2 = gm >> 12;
          int y = (gm >> 6) & 63;
          int x = gm & 63;
          int wv, sv;
          if (br2 == 0){ wv = x >> 1; sv = (y << 1) | (x & 1); }
          else         { wv = y >> 1; sv = ((y & 1) << 6) | x; }
          long row = ((long)bb2*32 + wv)*128 + sv;
          outb[(((long)(tile*2 + br2)*4 + hh)*32768L + row)*32 + d] = f2bf(v);
        }
      }
}

// ---------------- LayerNorm over C=256 ----------------
__global__ __launch_bounds__(256) void ln_k(const float* __restrict__ X,
    const float* __restrict__ g, const float* __restrict__ b,
    float* __restrict__ outf, ushort* __restrict__ outb)
{
  const int wid = threadIdx.x>>6, lane = threadIdx.x&63;
  const long row = (long)blockIdx.x*4 + wid;
  const float4 v = *(const float4*)&X[row*256 + lane*4];
  float s = v.x+v.y+v.z+v.w;
  #pragma unroll
  for (int m=1;m<64;m<<=1) s += __shfl_xor(s, m);
  float mu = s * (1.0f/256.0f);
  float d0=v.x-mu, d1=v.y-mu, d2=v.z-mu, d3=v.w-mu;
  float q = d0*d0+d1*d1+d2*d2+d3*d3;
  #pragma unroll
  for (int m=1;m<64;m<<=1) q += __shfl_xor(q, m);
  float rs = rsqrtf(q*(1.0f/256.0f) + EPSV);
  int c = lane*4;
  float o0 = d0*rs*g[c+0] + b[c+0];
  float o1 = d1*rs*g[c+1] + b[c+1];
  float o2 = d2*rs*g[c+2] + b[c+2];
  float o3 = d3*rs*g[c+3] + b[c+3];
  if (outf){ float4 o = {o0,o1,o2,o3}; *(float4*)&outf[row*256 + c] = o; }
  if (outb){
    ushort4 u; u.x=f2bf(o0); u.y=f2bf(o1); u.z=f2bf(o2); u.w=f2bf(o3);
    *(ushort4*)&outb[row*256 + c] = u;
  }
}

// ---------------- stripe-window attention + LePE (swapped-QK^T, in-register P) ----------------
// grid: x = win(0..31)*4 + head(0..3), y = batch(8). Template BR = branch.
template<int BR>
__global__ __launch_bounds__(256) void attn_k(
    const ushort* __restrict__ QKVw, ushort* __restrict__ ATT,
    const float* __restrict__ lepe_w, const float* __restrict__ lepe_b, int layer)
{
  __shared__ ushort q_lds[128][36];
  __shared__ ushort k_lds[128][36];
  __shared__ ushort vT[32][132];
  __shared__ float wl[32][9];
  __shared__ float bl[32];
  const int tid = threadIdx.x, wid = tid>>6, lane = tid&63;
  const int b = blockIdx.y;
  const int w = blockIdx.x>>2, h = blockIdx.x&3;
  const int choff = BR*128 + h*32;
  const int l15 = lane&15, lg = lane>>4;

  const long rowbase = ((long)b*32 + w)*128;
  const ushort* qb = QKVw + (((long)(0*2+BR)*4 + h)*32768L + rowbase)*32;
  const ushort* kb = QKVw + (((long)(1*2+BR)*4 + h)*32768L + rowbase)*32;
  const ushort* vb = QKVw + (((long)(2*2+BR)*4 + h)*32768L + rowbase)*32;

  for (int e = tid; e < 512; e += 256){
    int row = e>>2, c4 = (e&3)*8;
    *(uint4*)&q_lds[row][c4] = *(const uint4*)(qb + (long)e*8);
    *(uint4*)&k_lds[row][c4] = *(const uint4*)(kb + (long)e*8);
    uint4 val = *(const uint4*)(vb + (long)e*8);
    const ushort* u = (const ushort*)&val;
    #pragma unroll
    for (int jj=0;jj<8;jj++) vT[c4+jj][row] = u[jj];
  }
  for (int e = tid; e < 288; e += 256){
    int d = e/9, tap = e%9;
    wl[d][tap] = lepe_w[((long)((layer*2+BR)*128 + h*32 + d))*9 + tap];
  }
  if (tid < 32) bl[tid] = lepe_b[(layer*2+BR)*128 + h*32 + tid];
  __syncthreads();

  const int wrow = wid*32;
  const float scale = 0.17677669529663689f;
  const int srcE = (lane & 15) | ((lane & 16) << 1);  // source lane group 2*(lg&1)
  const int srcO = srcE + 16;                          // source lane group 2*(lg&1)+1
  const bool hi = (lane >= 32);                        // tile select: 2ks + (lg>>1)

  #pragma unroll
  for (int mi=0; mi<2; mi++){
    // swapped QK^T: D[t_loc][q_loc] => lane holds q = wrow+mi*16+l15, t = 16*ni + 4*lg + r
    s8v aq = *(const s8v*)&q_lds[wrow + mi*16 + l15][lg*8];
    f4v S[8];
    #pragma unroll
    for (int ni=0; ni<8; ni++){
      s8v bk = *(const s8v*)&k_lds[ni*16 + l15][lg*8];
      f4v z = {0.f,0.f,0.f,0.f};
      S[ni] = __builtin_amdgcn_mfma_f32_16x16x32_bf16(bk, aq, z, 0,0,0);
    }
    // in-register softmax over t (cross-lane over lg bits 16,32)
    float mx = -1e30f;
    #pragma unroll
    for (int ni=0; ni<8; ni++)
      #pragma unroll
      for (int r=0;r<4;r++){ S[ni][r] *= scale; mx = fmaxf(mx, S[ni][r]); }
    mx = fmaxf(mx, __shfl_xor(mx, 16));
    mx = fmaxf(mx, __shfl_xor(mx, 32));
    float sum = 0.f;
    #pragma unroll
    for (int ni=0; ni<8; ni++)
      #pragma unroll
      for (int r=0;r<4;r++){ S[ni][r] = __expf(S[ni][r]-mx); sum += S[ni][r]; }
    sum += __shfl_xor(sum, 16);
    sum += __shfl_xor(sum, 32);
    const float inv = 1.0f / sum;
    // pack P rows: Alo[ni] = (p[r0], p[r1]), Ahi[ni] = (p[r2], p[r3])
    unsigned int Alo[8], Ahi[8];
    #pragma unroll
    for (int ni=0; ni<8; ni++){
      Alo[ni] = (unsigned)f2bf(S[ni][0]*inv) | ((unsigned)f2bf(S[ni][1]*inv)<<16);
      Ahi[ni] = (unsigned)f2bf(S[ni][2]*inv) | ((unsigned)f2bf(S[ni][3]*inv)<<16);
    }
    // PV: build A-frag (row=q, k=t) via lane exchange, accumulate
    f4v acc2[2] = {{0.f,0.f,0.f,0.f},{0.f,0.f,0.f,0.f}};
    #pragma unroll
    for (int ks=0; ks<4; ks++){
      unsigned e0 = (unsigned)__shfl((int)Alo[2*ks],   srcE);
      unsigned e1 = (unsigned)__shfl((int)Ahi[2*ks],   srcE);
      unsigned e2 = (unsigned)__shfl((int)Alo[2*ks+1], srcE);
      unsigned e3 = (unsigned)__shfl((int)Ahi[2*ks+1], srcE);
      unsigned o0 = (unsigned)__shfl((int)Alo[2*ks],   srcO);
      unsigned o1 = (unsigned)__shfl((int)Ahi[2*ks],   srcO);
      unsigned o2 = (unsigned)__shfl((int)Alo[2*ks+1], srcO);
      unsigned o3 = (unsigned)__shfl((int)Ahi[2*ks+1], srcO);
      union { unsigned u[4]; s8v v; } ap;
      ap.u[0] = hi?e2:e0; ap.u[1] = hi?e3:e1; ap.u[2] = hi?o2:o0; ap.u[3] = hi?o3:o1;
      #pragma unroll
      for (int di=0; di<2; di++){
        s8v bv = *(const s8v*)&vT[di*16 + l15][ks*32 + lg*8];
        acc2[di] = __builtin_amdgcn_mfma_f32_16x16x32_bf16(ap.v, bv, acc2[di], 0,0,0);
      }
    }
    // epilogue: LePE + store (O layout: s = wrow+mi*16+lg*4+r, d = di*16+l15)
    #pragma unroll
    for (int di=0; di<2; di++)
      #pragma unroll
      for (int r=0;r<4;r++){
        int s = wrow + mi*16 + lg*4 + r;
        int d = di*16 + l15;
        float v = acc2[di][r] + bl[d];
        const int HsL = (BR==0)?64:2, WsL = (BR==0)?2:64;
        int hs, ws2;
        if (BR==0){ hs = s>>1; ws2 = s&1; }
        else      { hs = s>>6; ws2 = s&63; }
        #pragma unroll
        for (int a=-1;a<=1;a++)
          #pragma unroll
          for (int bb=-1;bb<=1;bb++){
            int h2 = hs+a, w2 = ws2+bb;
            if (h2>=0 && h2<HsL && w2>=0 && w2<WsL){
              int s2 = h2*WsL + w2;
              v += wl[d][(a+1)*3 + (bb+1)] * bf2f(vT[d][s2]);
            }
          }
        int y, x;
        if (BR==0){ y = s>>1; x = (w<<1)|(s&1); }
        else      { y = (w<<1)|(s>>6); x = s&63; }
        long tok = ((long)b*64 + y)*64 + x;
        ATT[tok*256 + choff + d] = f2bf(v);
      }
  }
}

// ---------------- final write: T [M][256] f32 -> d_out FLOAT32 (two NCHW halves) ----------------
__global__ __launch_bounds__(256) void write_out_k(const float* __restrict__ T, float* __restrict__ out){
  const long idx = (long)blockIdx.x*256 + threadIdx.x;
  const int half = (int)(idx >> 22);
  const long rem = idx & 4194303L;
  const int b = (int)(rem >> 19);
  const int c = (int)((rem >> 12) & 127);
  const int l = (int)(rem & 4095);
  out[idx] = T[((long)b*4096 + l)*256 + half*128 + c];
}

extern "C" void kernel_launch(void* const* d_in, const int* in_sizes, int n_in,
                              void* d_out, int out_size, void* d_ws, size_t ws_size,
                              hipStream_t stream)
{
  (void)in_sizes; (void)n_in; (void)out_size;
  const float* x1     = (const float*)d_in[0];
  const float* x2     = (const float*)d_in[1];
  const float* conv_w = (const float*)d_in[2];
  const float* conv_b = (const float*)d_in[3];
  const float* bn_g   = (const float*)d_in[4];
  const float* bn_b   = (const float*)d_in[5];
  const float* bn_m   = (const float*)d_in[6];
  const float* bn_v   = (const float*)d_in[7];
  const float* ln0_g  = (const float*)d_in[8];
  const float* ln0_b  = (const float*)d_in[9];
  const float* n1_g   = (const float*)d_in[10];
  const float* n1_b   = (const float*)d_in[11];
  const float* qkv_w  = (const float*)d_in[12];
  const float* lepe_w = (const float*)d_in[13];
  const float* lepe_b = (const float*)d_in[14];
  const float* proj_w = (const float*)d_in[15];
  const float* proj_b = (const float*)d_in[16];
  const float* n2_g   = (const float*)d_in[17];
  const float* n2_b   = (const float*)d_in[18];
  const float* fc1_w  = (const float*)d_in[19];
  const float* fc1_b  = (const float*)d_in[20];
  const float* fc2_w  = (const float*)d_in[21];
  const float* fc2_b  = (const float*)d_in[22];

  if (ws_size < 121767936ULL){
    hipMemsetAsync(d_out, 0, (size_t)out_size*4, stream);
    return;
  }

  char* ws = (char*)d_ws;
  ushort* QKVb = (ushort*)ws;          // R1 (67.1MB): QKVw(50.3MB)/H1b(67.1MB)/TMPf(33.5MB) disjoint
  ushort* H1b  = (ushort*)ws;
  float*  TMPf = (float*)ws;
  size_t off = 67108864;
  float*  T    = (float*)(ws + off);
  ushort* Xin  = (ushort*)(ws + off);  // alias: Xin dead before T first written
  off += 33554432;
  ushort* Xb   = (ushort*)(ws + off);
  ushort* ATTb = (ushort*)(ws + off);  // alias: lifetimes interleave, never overlap
  off += 16777216;
  ushort* Wc   = (ushort*)(ws + off); off += 1179648;
  ushort* Wq   = (ushort*)(ws + off); off += 786432;
  ushort* Wp   = (ushort*)(ws + off); off += 262144;
  ushort* W1   = (ushort*)(ws + off); off += 1048576;
  ushort* W2   = (ushort*)(ws + off); off += 1048576;
  float*  scv  = (float*)(ws + off);  off += 1024;
  float*  shv  = (float*)(ws + off);  off += 1024;

  hipMemsetAsync(Xin, 0, (size_t)8*66*66*256*2, stream);
  repack_in_k<<<dim3(64,8), 256, 0, stream>>>(x1, x2, Xin);
  repack_convw_k<<<576, 256, 0, stream>>>(conv_w, Wc);
  for (int i=0;i<2;i++){
    transpose_w_k<<<512,256,0,stream>>>(qkv_w + (long)i*196608, Wq + (long)i*196608, 256, 768);
    transpose_w_k<<<128,256,0,stream>>>(proj_w + (long)i*65536, Wp + (long)i*65536, 256, 256);
    transpose_w_k<<<512,256,0,stream>>>(fc1_w + (long)i*262144, W1 + (long)i*262144, 256, 1024);
    transpose_w_k<<<512,256,0,stream>>>(fc2_w + (long)i*262144, W2 + (long)i*262144, 1024, 256);
  }
  bnprep_k<<<1,256,0,stream>>>(conv_b, bn_g, bn_b, bn_m, bn_v, scv, shv);

  // conv 3x3 + BN (implicit GEMM, K=2304) -> TMPf f32
  gemm_k<3,true><<<dim3(256,2),256,0,stream>>>(nullptr, Xin, Wc, nullptr, scv, shv,
                                               nullptr, nullptr, TMPf, 256, 2304);
  // LN0 -> T
  ln_k<<<8192,256,0,stream>>>(TMPf, ln0_g, ln0_b, T, nullptr);

  for (int i=0;i<2;i++){
    ln_k<<<8192,256,0,stream>>>(T, n1_g + i*256, n1_b + i*256, nullptr, Xb);
    gemm_k<4,false><<<dim3(256,6),256,0,stream>>>(Xb, nullptr, Wq + (long)i*196608, nullptr,
                                                  nullptr, nullptr, nullptr, QKVb, nullptr, 768, 256);
    attn_k<0><<<dim3(128,8),256,0,stream>>>(QKVb, ATTb, lepe_w, lepe_b, i);
    attn_k<1><<<dim3(128,8),256,0,stream>>>(QKVb, ATTb, lepe_w, lepe_b, i);
    gemm_k<2,false><<<dim3(256,2),256,0,stream>>>(ATTb, nullptr, Wp + (long)i*65536, proj_b + i*256,
                                                  nullptr, nullptr, T, nullptr, nullptr, 256, 256);
    ln_k<<<8192,256,0,stream>>>(T, n2_g + i*256, n2_b + i*256, nullptr, Xb);
    gemm_k<1,false><<<dim3(256,8),256,0,stream>>>(Xb, nullptr, W1 + (long)i*262144, fc1_b + i*1024,
                                                  nullptr, nullptr, nullptr, H1b, nullptr, 1024, 256);
    gemm_k<2,false><<<dim3(256,2),256,0,stream>>>(H1b, nullptr, W2 + (long)i*262144, fc2_b + i*256,
                                                  nullptr, nullptr, T, nullptr, nullptr, 256, 1024);
  }
  write_out_k<<<32768,256,0,stream>>>(T, (float*)d_out);
}

// Round 11
// 558.569 us; speedup vs baseline: 1.1212x; 1.0551x over previous
//
#include <hip/hip_runtime.h>
#include <hip/hip_bf16.h>

#define EPSV 1e-5f

using s8v = __attribute__((ext_vector_type(8))) short;
using f4v = __attribute__((ext_vector_type(4))) float;

__device__ __forceinline__ float bf2f(ushort u){
  union { unsigned int i; float f; } x; x.i = ((unsigned int)u)<<16; return x.f;
}
__device__ __forceinline__ ushort f2bf(float f){
  union { float f; unsigned int i; } x; x.f = f;
  unsigned int r = x.i + 0x7FFFu + ((x.i>>16)&1u);
  return (ushort)(r>>16);
}

__device__ __forceinline__ void gload16(const void* g, void* l){
  __builtin_amdgcn_global_load_lds((__attribute__((address_space(1))) void*)g,
                                   (__attribute__((address_space(3))) void*)l, 16, 0, 0);
}

// ---------------- input repack: NCHW f32 (x1|x2) -> padded NHWC bf16 [8][66][66][256] ----------------
__global__ __launch_bounds__(256) void repack_in_k(const float* __restrict__ x1,
                                                   const float* __restrict__ x2,
                                                   ushort* __restrict__ Xin){
  __shared__ ushort tile[256][66];
  const int y = blockIdx.x, b = blockIdx.y, tid = threadIdx.x;
  const int xl = tid & 63, cq = tid >> 6;
  for (int it=0; it<64; it++){
    int ci = it*4 + cq;
    float v;
    if (ci < 128) v = x1[(((long)b*128 + ci)*64 + y)*64 + xl];
    else          v = x2[(((long)b*128 + (ci-128))*64 + y)*64 + xl];
    tile[ci][xl] = f2bf(v);
  }
  __syncthreads();
  for (int x=0; x<64; x++){
    Xin[(((long)b*66 + (y+1))*66 + (x+1))*256 + tid] = tile[tid][x];
  }
}

// ---------------- conv weight repack: Wc[co][dd*256+ci] = w[co][ci][dd] ----------------
__global__ void repack_convw_k(const float* __restrict__ w, ushort* __restrict__ Wc){
  const long total = 256L*2304;
  for (long e = (long)blockIdx.x*blockDim.x + threadIdx.x; e < total; e += (long)gridDim.x*blockDim.x){
    int co = (int)(e / 2304), kk = (int)(e % 2304);
    int dd = kk >> 8, ci = kk & 255;
    Wc[e] = f2bf(w[((long)(co*256 + ci))*9 + dd]);
  }
}

// ---------------- weight transpose f32[K][N] -> bf16[N][K] ----------------
__global__ void transpose_w_k(const float* __restrict__ src, ushort* __restrict__ dst, int K, int N){
  long total = (long)K*N;
  for (long e = (long)blockIdx.x*blockDim.x + threadIdx.x; e < total; e += (long)gridDim.x*blockDim.x){
    int k = (int)(e / N), n = (int)(e % N);
    dst[(long)n*K + k] = f2bf(src[e]);
  }
}

__global__ void bnprep_k(const float* cb, const float* g, const float* b,
                         const float* m, const float* v, float* sc, float* sh){
  int n = threadIdx.x;
  if (n < 256){
    float s = g[n] * rsqrtf(v[n] + EPSV);
    sc[n] = s;
    sh[n] = (cb[n] - m[n])*s + b[n];
  }
}

// ---------------- MFMA GEMM: C = A[M][K] @ Wt[N][K]^T ----------------
// EPI: 0 bf16 store; 1 bf16 bias+GELU; 2 f32 resid += v+bias; 3 f32 conv-BN; 4 qkv window-permuted bf16
// BNV: 128 (2 blocks/CU shapes) or 64 (doubles grid for N=256 GEMMs)
#define BM 128
#define BK 64
template<int EPI, bool CONVA, int BNV>
__global__ __launch_bounds__(256) void gemm_k(
    const ushort* __restrict__ A, const ushort* __restrict__ Xin,
    const ushort* __restrict__ Wt, const float* __restrict__ bias,
    const float* __restrict__ sc, const float* __restrict__ sh,
    float* __restrict__ resid, ushort* __restrict__ outb, float* __restrict__ outf,
    int N, int K)
{
  constexpr int NI = BNV/32;        // B col-fragments per wave
  constexpr int JB = BNV/32;        // B staging 8-row slabs per wave
  __shared__ ushort As[BM*BK];
  __shared__ ushort Bs[BNV*BK];
  const int tid = threadIdx.x, wid = tid>>6, lane = tid&63;
  const int m0 = blockIdx.x*BM, n0 = blockIdx.y*BNV;
  const int wm = (wid>>1)*64, wn = (wid&1)*(BNV/2);
  const int l15 = lane&15, lg = lane>>4;

  const int rA = wid*32 + (lane>>3);
  const int rB = wid*(BNV/4) + (lane>>3);
  const int cA = (lane&7)*8;
  const ushort* pA[4];
  if (CONVA){
    #pragma unroll
    for (int j=0;j<4;j++){
      int t = m0 + rA + j*8;
      int b = t>>12, y = (t>>6)&63, x = t&63;
      pA[j] = Xin + ((long)((b*66 + y+1)*66) + (x+1))*256 + cA;
    }
  } else {
    #pragma unroll
    for (int j=0;j<4;j++) pA[j] = A + (long)(m0 + rA + j*8)*K + cA;
  }
  const ushort* pB[JB];
  #pragma unroll
  for (int j=0;j<JB;j++) pB[j] = Wt + (long)(n0 + rB + j*8)*K + cA;

  f4v acc[4][NI] = {};

  for (int k0=0; k0<K; k0+=BK){
    int koffA;
    if (CONVA){
      int dd = k0 >> 8;
      int dy = dd/3, dx = dd - dy*3;
      koffA = ((dy-1)*66 + (dx-1))*256 + (k0 & 255);
    } else koffA = k0;
    #pragma unroll
    for (int j=0;j<4;j++)
      gload16(pA[j] + koffA, (void*)&As[(wid*32 + j*8)*BK]);
    #pragma unroll
    for (int j=0;j<JB;j++)
      gload16(pB[j] + k0, (void*)&Bs[(wid*(BNV/4) + j*8)*BK]);
    __syncthreads();
    #pragma unroll
    for (int kk=0; kk<2; kk++){
      s8v a[4], b[NI];
      const int ke = kk*32 + lg*8;
      #pragma unroll
      for (int mi=0;mi<4;mi++) a[mi] = *(const s8v*)&As[(wm + mi*16 + l15)*BK + ke];
      #pragma unroll
      for (int ni=0;ni<NI;ni++) b[ni] = *(const s8v*)&Bs[(wn + ni*16 + l15)*BK + ke];
      #pragma unroll
      for (int mi=0;mi<4;mi++)
        #pragma unroll
        for (int ni=0;ni<NI;ni++)
          acc[mi][ni] = __builtin_amdgcn_mfma_f32_16x16x32_bf16(a[mi], b[ni], acc[mi][ni], 0,0,0);
    }
    __syncthreads();
  }

  #pragma unroll
  for (int mi=0;mi<4;mi++)
    #pragma unroll
    for (int ni=0;ni<NI;ni++)
      #pragma unroll
      for (int r=0;r<4;r++){
        int gm = m0 + wm + mi*16 + lg*4 + r;
        int gn = n0 + wn + ni*16 + l15;
        float v = acc[mi][ni][r];
        if (EPI==0){
          outb[(long)gm*N + gn] = f2bf(v);
        } else if (EPI==1){
          v += bias[gn];
          v = 0.5f*v*(1.0f + erff(v*0.70710678118654752f));
          outb[(long)gm*N + gn] = f2bf(v);
        } else if (EPI==2){
          resid[(long)gm*N + gn] += v + bias[gn];
        } else if (EPI==3){
          outf[(long)gm*N + gn] = v*sc[gn] + sh[gn];
        } else {
          // EPI==4: window-ordered QKV store: [tile(3)][br(2)][head(4)][(b*32+w)*128+s][32]
          int tile = gn >> 8;
          int c = gn & 255;
          int br2 = (c >> 7) & 1;
          int hh = (c >> 5) & 3;
          int d = c & 31;
          int bb2 = gm >> 12;
          int y = (gm >> 6) & 63;
          int x = gm & 63;
          int wv, sv;
          if (br2 == 0){ wv = x >> 1; sv = (y << 1) | (x & 1); }
          else         { wv = y >> 1; sv = ((y & 1) << 6) | x; }
          long row = ((long)bb2*32 + wv)*128 + sv;
          outb[(((long)(tile*2 + br2)*4 + hh)*32768L + row)*32 + d] = f2bf(v);
        }
      }
}

// ---------------- LayerNorm over C=256 ----------------
__global__ __launch_bounds__(256) void ln_k(const float* __restrict__ X,
    const float* __restrict__ g, const float* __restrict__ b,
    float* __restrict__ outf, ushort* __restrict__ outb)
{
  const int wid = threadIdx.x>>6, lane = threadIdx.x&63;
  const long row = (long)blockIdx.x*4 + wid;
  const float4 v = *(const float4*)&X[row*256 + lane*4];
  float s = v.x+v.y+v.z+v.w;
  #pragma unroll
  for (int m=1;m<64;m<<=1) s += __shfl_xor(s, m);
  float mu = s * (1.0f/256.0f);
  float d0=v.x-mu, d1=v.y-mu, d2=v.z-mu, d3=v.w-mu;
  float q = d0*d0+d1*d1+d2*d2+d3*d3;
  #pragma unroll
  for (int m=1;m<64;m<<=1) q += __shfl_xor(q, m);
  float rs = rsqrtf(q*(1.0f/256.0f) + EPSV);
  int c = lane*4;
  float o0 = d0*rs*g[c+0] + b[c+0];
  float o1 = d1*rs*g[c+1] + b[c+1];
  float o2 = d2*rs*g[c+2] + b[c+2];
  float o3 = d3*rs*g[c+3] + b[c+3];
  if (outf){ float4 o = {o0,o1,o2,o3}; *(float4*)&outf[row*256 + c] = o; }
  if (outb){
    ushort4 u; u.x=f2bf(o0); u.y=f2bf(o1); u.z=f2bf(o2); u.w=f2bf(o3);
    *(ushort4*)&outb[row*256 + c] = u;
  }
}

// ---------------- stripe-window attention + LePE (swapped-QK^T, in-register P) ----------------
template<int BR>
__global__ __launch_bounds__(256) void attn_k(
    const ushort* __restrict__ QKVw, ushort* __restrict__ ATT,
    const float* __restrict__ lepe_w, const float* __restrict__ lepe_b, int layer)
{
  __shared__ ushort q_lds[128][36];
  __shared__ ushort k_lds[128][36];
  __shared__ ushort vT[32][132];
  __shared__ float wl[32][9];
  __shared__ float bl[32];
  const int tid = threadIdx.x, wid = tid>>6, lane = tid&63;
  const int b = blockIdx.y;
  const int w = blockIdx.x>>2, h = blockIdx.x&3;
  const int choff = BR*128 + h*32;
  const int l15 = lane&15, lg = lane>>4;

  const long rowbase = ((long)b*32 + w)*128;
  const ushort* qb = QKVw + (((long)(0*2+BR)*4 + h)*32768L + rowbase)*32;
  const ushort* kb = QKVw + (((long)(1*2+BR)*4 + h)*32768L + rowbase)*32;
  const ushort* vb = QKVw + (((long)(2*2+BR)*4 + h)*32768L + rowbase)*32;

  for (int e = tid; e < 512; e += 256){
    int row = e>>2, c4 = (e&3)*8;
    *(uint4*)&q_lds[row][c4] = *(const uint4*)(qb + (long)e*8);
    *(uint4*)&k_lds[row][c4] = *(const uint4*)(kb + (long)e*8);
    uint4 val = *(const uint4*)(vb + (long)e*8);
    const ushort* u = (const ushort*)&val;
    #pragma unroll
    for (int jj=0;jj<8;jj++) vT[c4+jj][row] = u[jj];
  }
  for (int e = tid; e < 288; e += 256){
    int d = e/9, tap = e%9;
    wl[d][tap] = lepe_w[((long)((layer*2+BR)*128 + h*32 + d))*9 + tap];
  }
  if (tid < 32) bl[tid] = lepe_b[(layer*2+BR)*128 + h*32 + tid];
  __syncthreads();

  const int wrow = wid*32;
  const float scale = 0.17677669529663689f;
  const int srcE = (lane & 15) | ((lane & 16) << 1);
  const int srcO = srcE + 16;
  const bool hi = (lane >= 32);

  #pragma unroll
  for (int mi=0; mi<2; mi++){
    s8v aq = *(const s8v*)&q_lds[wrow + mi*16 + l15][lg*8];
    f4v S[8];
    #pragma unroll
    for (int ni=0; ni<8; ni++){
      s8v bk = *(const s8v*)&k_lds[ni*16 + l15][lg*8];
      f4v z = {0.f,0.f,0.f,0.f};
      S[ni] = __builtin_amdgcn_mfma_f32_16x16x32_bf16(bk, aq, z, 0,0,0);
    }
    float mx = -1e30f;
    #pragma unroll
    for (int ni=0; ni<8; ni++)
      #pragma unroll
      for (int r=0;r<4;r++){ S[ni][r] *= scale; mx = fmaxf(mx, S[ni][r]); }
    mx = fmaxf(mx, __shfl_xor(mx, 16));
    mx = fmaxf(mx, __shfl_xor(mx, 32));
    float sum = 0.f;
    #pragma unroll
    for (int ni=0; ni<8; ni++)
      #pragma unroll
      for (int r=0;r<4;r++){ S[ni][r] = __expf(S[ni][r]-mx); sum += S[ni][r]; }
    sum += __shfl_xor(sum, 16);
    sum += __shfl_xor(sum, 32);
    const float inv = 1.0f / sum;
    unsigned int Alo[8], Ahi[8];
    #pragma unroll
    for (int ni=0; ni<8; ni++){
      Alo[ni] = (unsigned)f2bf(S[ni][0]*inv) | ((unsigned)f2bf(S[ni][1]*inv)<<16);
      Ahi[ni] = (unsigned)f2bf(S[ni][2]*inv) | ((unsigned)f2bf(S[ni][3]*inv)<<16);
    }
    f4v acc2[2] = {{0.f,0.f,0.f,0.f},{0.f,0.f,0.f,0.f}};
    #pragma unroll
    for (int ks=0; ks<4; ks++){
      unsigned e0 = (unsigned)__shfl((int)Alo[2*ks],   srcE);
      unsigned e1 = (unsigned)__shfl((int)Ahi[2*ks],   srcE);
      unsigned e2 = (unsigned)__shfl((int)Alo[2*ks+1], srcE);
      unsigned e3 = (unsigned)__shfl((int)Ahi[2*ks+1], srcE);
      unsigned o0 = (unsigned)__shfl((int)Alo[2*ks],   srcO);
      unsigned o1 = (unsigned)__shfl((int)Ahi[2*ks],   srcO);
      unsigned o2 = (unsigned)__shfl((int)Alo[2*ks+1], srcO);
      unsigned o3 = (unsigned)__shfl((int)Ahi[2*ks+1], srcO);
      union { unsigned u[4]; s8v v; } ap;
      ap.u[0] = hi?e2:e0; ap.u[1] = hi?e3:e1; ap.u[2] = hi?o2:o0; ap.u[3] = hi?o3:o1;
      #pragma unroll
      for (int di=0; di<2; di++){
        s8v bv = *(const s8v*)&vT[di*16 + l15][ks*32 + lg*8];
        acc2[di] = __builtin_amdgcn_mfma_f32_16x16x32_bf16(ap.v, bv, acc2[di], 0,0,0);
      }
    }
    #pragma unroll
    for (int di=0; di<2; di++)
      #pragma unroll
      for (int r=0;r<4;r++){
        int s = wrow + mi*16 + lg*4 + r;
        int d = di*16 + l15;
        float v = acc2[di][r] + bl[d];
        const int HsL = (BR==0)?64:2, WsL = (BR==0)?2:64;
        int hs, ws2;
        if (BR==0){ hs = s>>1; ws2 = s&1; }
        else      { hs = s>>6; ws2 = s&63; }
        #pragma unroll
        for (int a=-1;a<=1;a++)
          #pragma unroll
          for (int bb=-1;bb<=1;bb++){
            int h2 = hs+a, w2 = ws2+bb;
            if (h2>=0 && h2<HsL && w2>=0 && w2<WsL){
              int s2 = h2*WsL + w2;
              v += wl[d][(a+1)*3 + (bb+1)] * bf2f(vT[d][s2]);
            }
          }
        int y, x;
        if (BR==0){ y = s>>1; x = (w<<1)|(s&1); }
        else      { y = (w<<1)|(s>>6); x = s&63; }
        long tok = ((long)b*64 + y)*64 + x;
        ATT[tok*256 + choff + d] = f2bf(v);
      }
  }
}

// ---------------- final write: T [tok][256] f32 -> d_out f32 NCHW halves (LDS-tiled, coalesced) ----------------
// grid (64 y, 8 b, 2 half); out[half*4M + b*512K + c*4096 + y*64 + x] = T[(b*4096 + y*64 + x)*256 + half*128 + c]
__global__ __launch_bounds__(256) void write_out_k(const float* __restrict__ T, float* __restrict__ out){
  __shared__ float tile[64][133];
  const int y = blockIdx.x, b = blockIdx.y, half = blockIdx.z;
  const int tid = threadIdx.x;
  {
    const int c = tid & 127, xh = tid >> 7;
    #pragma unroll
    for (int i=0;i<32;i++){
      int x = i*2 + xh;
      tile[x][c] = T[(((long)b*64 + y)*64 + x)*256 + half*128 + c];
    }
  }
  __syncthreads();
  {
    const int x = tid & 63, ch = tid >> 6;
    float* op = out + (long)half*4194304 + (long)b*524288 + (long)y*64;
    #pragma unroll
    for (int i=0;i<32;i++){
      int c = i*4 + ch;
      op[(long)c*4096 + x] = tile[x][c];
    }
  }
}

extern "C" void kernel_launch(void* const* d_in, const int* in_sizes, int n_in,
                              void* d_out, int out_size, void* d_ws, size_t ws_size,
                              hipStream_t stream)
{
  (void)in_sizes; (void)n_in; (void)out_size;
  const float* x1     = (const float*)d_in[0];
  const float* x2     = (const float*)d_in[1];
  const float* conv_w = (const float*)d_in[2];
  const float* conv_b = (const float*)d_in[3];
  const float* bn_g   = (const float*)d_in[4];
  const float* bn_b   = (const float*)d_in[5];
  const float* bn_m   = (const float*)d_in[6];
  const float* bn_v   = (const float*)d_in[7];
  const float* ln0_g  = (const float*)d_in[8];
  const float* ln0_b  = (const float*)d_in[9];
  const float* n1_g   = (const float*)d_in[10];
  const float* n1_b   = (const float*)d_in[11];
  const float* qkv_w  = (const float*)d_in[12];
  const float* lepe_w = (const float*)d_in[13];
  const float* lepe_b = (const float*)d_in[14];
  const float* proj_w = (const float*)d_in[15];
  const float* proj_b = (const float*)d_in[16];
  const float* n2_g   = (const float*)d_in[17];
  const float* n2_b   = (const float*)d_in[18];
  const float* fc1_w  = (const float*)d_in[19];
  const float* fc1_b  = (const float*)d_in[20];
  const float* fc2_w  = (const float*)d_in[21];
  const float* fc2_b  = (const float*)d_in[22];

  if (ws_size < 121767936ULL){
    hipMemsetAsync(d_out, 0, (size_t)out_size*4, stream);
    return;
  }

  char* ws = (char*)d_ws;
  ushort* QKVb = (ushort*)ws;          // R1 (67.1MB): QKVw(50.3MB)/H1b(67.1MB)/TMPf(33.5MB) disjoint
  ushort* H1b  = (ushort*)ws;
  float*  TMPf = (float*)ws;
  size_t off = 67108864;
  float*  T    = (float*)(ws + off);
  ushort* Xin  = (ushort*)(ws + off);  // alias: Xin dead before T first written
  off += 33554432;
  ushort* Xb   = (ushort*)(ws + off);
  ushort* ATTb = (ushort*)(ws + off);  // alias: lifetimes interleave, never overlap
  off += 16777216;
  ushort* Wc   = (ushort*)(ws + off); off += 1179648;
  ushort* Wq   = (ushort*)(ws + off); off += 786432;
  ushort* Wp   = (ushort*)(ws + off); off += 262144;
  ushort* W1   = (ushort*)(ws + off); off += 1048576;
  ushort* W2   = (ushort*)(ws + off); off += 1048576;
  float*  scv  = (float*)(ws + off);  off += 1024;
  float*  shv  = (float*)(ws + off);  off += 1024;

  hipMemsetAsync(Xin, 0, (size_t)8*66*66*256*2, stream);
  repack_in_k<<<dim3(64,8), 256, 0, stream>>>(x1, x2, Xin);
  repack_convw_k<<<576, 256, 0, stream>>>(conv_w, Wc);
  for (int i=0;i<2;i++){
    transpose_w_k<<<512,256,0,stream>>>(qkv_w + (long)i*196608, Wq + (long)i*196608, 256, 768);
    transpose_w_k<<<128,256,0,stream>>>(proj_w + (long)i*65536, Wp + (long)i*65536, 256, 256);
    transpose_w_k<<<512,256,0,stream>>>(fc1_w + (long)i*262144, W1 + (long)i*262144, 256, 1024);
    transpose_w_k<<<512,256,0,stream>>>(fc2_w + (long)i*262144, W2 + (long)i*262144, 1024, 256);
  }
  bnprep_k<<<1,256,0,stream>>>(conv_b, bn_g, bn_b, bn_m, bn_v, scv, shv);

  // conv 3x3 + BN (implicit GEMM, K=2304), BN=64 tile -> 1024 blocks
  gemm_k<3,true,64><<<dim3(256,4),256,0,stream>>>(nullptr, Xin, Wc, nullptr, scv, shv,
                                                  nullptr, nullptr, TMPf, 256, 2304);
  // LN0 -> T
  ln_k<<<8192,256,0,stream>>>(TMPf, ln0_g, ln0_b, T, nullptr);

  for (int i=0;i<2;i++){
    ln_k<<<8192,256,0,stream>>>(T, n1_g + i*256, n1_b + i*256, nullptr, Xb);
    gemm_k<4,false,128><<<dim3(256,6),256,0,stream>>>(Xb, nullptr, Wq + (long)i*196608, nullptr,
                                                      nullptr, nullptr, nullptr, QKVb, nullptr, 768, 256);
    attn_k<0><<<dim3(128,8),256,0,stream>>>(QKVb, ATTb, lepe_w, lepe_b, i);
    attn_k<1><<<dim3(128,8),256,0,stream>>>(QKVb, ATTb, lepe_w, lepe_b, i);
    gemm_k<2,false,64><<<dim3(256,4),256,0,stream>>>(ATTb, nullptr, Wp + (long)i*65536, proj_b + i*256,
                                                     nullptr, nullptr, T, nullptr, nullptr, 256, 256);
    ln_k<<<8192,256,0,stream>>>(T, n2_g + i*256, n2_b + i*256, nullptr, Xb);
    gemm_k<1,false,128><<<dim3(256,8),256,0,stream>>>(Xb, nullptr, W1 + (long)i*262144, fc1_b + i*1024,
                                                      nullptr, nullptr, nullptr, H1b, nullptr, 1024, 256);
    gemm_k<2,false,64><<<dim3(256,4),256,0,stream>>>(H1b, nullptr, W2 + (long)i*262144, fc2_b + i*256,
                                                     nullptr, nullptr, T, nullptr, nullptr, 256, 1024);
  }
  write_out_k<<<dim3(64,8,2),256,0,stream>>>(T, (float*)d_out);
}

// Round 12
// 539.685 us; speedup vs baseline: 1.1604x; 1.0350x over previous
//
#include <hip/hip_runtime.h>
#include <hip/hip_bf16.h>

#define EPSV 1e-5f

using s8v = __attribute__((ext_vector_type(8))) short;
using f4v = __attribute__((ext_vector_type(4))) float;

__device__ __forceinline__ float bf2f(ushort u){
  union { unsigned int i; float f; } x; x.i = ((unsigned int)u)<<16; return x.f;
}
__device__ __forceinline__ ushort f2bf(float f){
  union { float f; unsigned int i; } x; x.f = f;
  unsigned int r = x.i + 0x7FFFu + ((x.i>>16)&1u);
  return (ushort)(r>>16);
}

__device__ __forceinline__ void gload16(const void* g, void* l){
  __builtin_amdgcn_global_load_lds((__attribute__((address_space(1))) void*)g,
                                   (__attribute__((address_space(3))) void*)l, 16, 0, 0);
}

// ---------------- input repack: NCHW f32 (x1|x2) -> padded NHWC bf16 [8][66][66][256] ----------------
__global__ __launch_bounds__(256) void repack_in_k(const float* __restrict__ x1,
                                                   const float* __restrict__ x2,
                                                   ushort* __restrict__ Xin){
  __shared__ ushort tile[256][66];
  const int y = blockIdx.x, b = blockIdx.y, tid = threadIdx.x;
  const int xl = tid & 63, cq = tid >> 6;
  for (int it=0; it<64; it++){
    int ci = it*4 + cq;
    float v;
    if (ci < 128) v = x1[(((long)b*128 + ci)*64 + y)*64 + xl];
    else          v = x2[(((long)b*128 + (ci-128))*64 + y)*64 + xl];
    tile[ci][xl] = f2bf(v);
  }
  __syncthreads();
  for (int x=0; x<64; x++){
    Xin[(((long)b*66 + (y+1))*66 + (x+1))*256 + tid] = tile[tid][x];
  }
}

// ---------------- conv weight repack: Wc[co][dd*256+ci] = w[co][ci][dd] ----------------
__global__ void repack_convw_k(const float* __restrict__ w, ushort* __restrict__ Wc){
  const long total = 256L*2304;
  for (long e = (long)blockIdx.x*blockDim.x + threadIdx.x; e < total; e += (long)gridDim.x*blockDim.x){
    int co = (int)(e / 2304), kk = (int)(e % 2304);
    int dd = kk >> 8, ci = kk & 255;
    Wc[e] = f2bf(w[((long)(co*256 + ci))*9 + dd]);
  }
}

// ---------------- weight transpose f32[K][N] -> bf16[N][K] ----------------
__global__ void transpose_w_k(const float* __restrict__ src, ushort* __restrict__ dst, int K, int N){
  long total = (long)K*N;
  for (long e = (long)blockIdx.x*blockDim.x + threadIdx.x; e < total; e += (long)gridDim.x*blockDim.x){
    int k = (int)(e / N), n = (int)(e % N);
    dst[(long)n*K + k] = f2bf(src[e]);
  }
}

__global__ void bnprep_k(const float* cb, const float* g, const float* b,
                         const float* m, const float* v, float* sc, float* sh){
  int n = threadIdx.x;
  if (n < 256){
    float s = g[n] * rsqrtf(v[n] + EPSV);
    sc[n] = s;
    sh[n] = (cb[n] - m[n])*s + b[n];
  }
}

// ---------------- MFMA GEMM: C = A[M][K] @ Wt[N][K]^T, BM=BN=128 ----------------
// EPI: 1 bf16 bias+GELU; 2 f32 resid += v+bias; 3 f32 conv-BN; 4 qkv window-permuted bf16
#define BM 128
#define BN 128
#define BK 64
template<int EPI, bool CONVA>
__global__ __launch_bounds__(256) void gemm_k(
    const ushort* __restrict__ A, const ushort* __restrict__ Xin,
    const ushort* __restrict__ Wt, const float* __restrict__ bias,
    const float* __restrict__ sc, const float* __restrict__ sh,
    float* __restrict__ resid, ushort* __restrict__ outb, float* __restrict__ outf,
    int N, int K)
{
  __shared__ ushort SMEM[BM*BK + BN*BK];   // As | Bs ; aliased as f32 CT[64][128] in epilogue
  ushort* As = SMEM;
  ushort* Bs = SMEM + BM*BK;
  const int tid = threadIdx.x, wid = tid>>6, lane = tid&63;
  const int m0 = blockIdx.x*BM, n0 = blockIdx.y*BN;
  const int wm = (wid>>1)*64, wn = (wid&1)*64;
  const int l15 = lane&15, lg = lane>>4;

  const int rA = wid*32 + (lane>>3);
  const int cA = (lane&7)*8;
  const ushort* pA[4];
  if (CONVA){
    #pragma unroll
    for (int j=0;j<4;j++){
      int t = m0 + rA + j*8;
      int b = t>>12, y = (t>>6)&63, x = t&63;
      pA[j] = Xin + ((long)((b*66 + y+1)*66) + (x+1))*256 + cA;
    }
  } else {
    #pragma unroll
    for (int j=0;j<4;j++) pA[j] = A + (long)(m0 + rA + j*8)*K + cA;
  }
  const ushort* pB[4];
  #pragma unroll
  for (int j=0;j<4;j++) pB[j] = Wt + (long)(n0 + rA + j*8)*K + cA;

  f4v acc[4][4] = {};

  for (int k0=0; k0<K; k0+=BK){
    int koffA;
    if (CONVA){
      int dd = k0 >> 8;
      int dy = dd/3, dx = dd - dy*3;
      koffA = ((dy-1)*66 + (dx-1))*256 + (k0 & 255);
    } else koffA = k0;
    #pragma unroll
    for (int j=0;j<4;j++){
      gload16(pA[j] + koffA, (void*)&As[(wid*32 + j*8)*BK]);
      gload16(pB[j] + k0,   (void*)&Bs[(wid*32 + j*8)*BK]);
    }
    __syncthreads();
    #pragma unroll
    for (int kk=0; kk<2; kk++){
      s8v a[4], b[4];
      const int ke = kk*32 + lg*8;
      #pragma unroll
      for (int mi=0;mi<4;mi++) a[mi] = *(const s8v*)&As[(wm + mi*16 + l15)*BK + ke];
      #pragma unroll
      for (int ni=0;ni<4;ni++) b[ni] = *(const s8v*)&Bs[(wn + ni*16 + l15)*BK + ke];
      #pragma unroll
      for (int mi=0;mi<4;mi++)
        #pragma unroll
        for (int ni=0;ni<4;ni++)
          acc[mi][ni] = __builtin_amdgcn_mfma_f32_16x16x32_bf16(a[mi], b[ni], acc[mi][ni], 0,0,0);
    }
    __syncthreads();
  }

  if (EPI == 4){
    // qkv window-permuted scatter (32-elem granularity; keep per-element path)
    #pragma unroll
    for (int mi=0;mi<4;mi++)
      #pragma unroll
      for (int ni=0;ni<4;ni++)
        #pragma unroll
        for (int r=0;r<4;r++){
          int gm = m0 + wm + mi*16 + lg*4 + r;
          int gn = n0 + wn + ni*16 + l15;
          float v = acc[mi][ni][r];
          int tile = gn >> 8;
          int c = gn & 255;
          int br2 = (c >> 7) & 1;
          int hh = (c >> 5) & 3;
          int d = c & 31;
          int bb2 = gm >> 12;
          int y = (gm >> 6) & 63;
          int x = gm & 63;
          int wv, sv;
          if (br2 == 0){ wv = x >> 1; sv = (y << 1) | (x & 1); }
          else         { wv = y >> 1; sv = ((y & 1) << 6) | x; }
          long row = ((long)bb2*32 + wv)*128 + sv;
          outb[(((long)(tile*2 + br2)*4 + hh)*32768L + row)*32 + d] = f2bf(v);
        }
  } else {
    // LDS-bounced, float4-coalesced epilogue (two 64-row passes through 32KB CT)
    float* CT = (float*)SMEM;
    #pragma unroll
    for (int p=0; p<2; p++){
      if ((wid>>1) == p){
        #pragma unroll
        for (int mi=0;mi<4;mi++)
          #pragma unroll
          for (int ni=0;ni<4;ni++)
            #pragma unroll
            for (int r=0;r<4;r++)
              CT[(mi*16 + lg*4 + r)*128 + wn + ni*16 + l15] = acc[mi][ni][r];
      }
      __syncthreads();
      #pragma unroll
      for (int it=0; it<8; it++){
        int e = it*256 + tid;        // 0..2047
        int row = e >> 5;            // 0..63
        int c4 = e & 31;             // float4 col
        float4 v = *(float4*)&CT[row*128 + c4*4];
        int gm = m0 + p*64 + row;
        int gn = n0 + c4*4;
        if (EPI == 1){
          float4 bv = *(const float4*)&bias[gn];
          float t0 = v.x + bv.x, t1 = v.y + bv.y, t2 = v.z + bv.z, t3 = v.w + bv.w;
          t0 = 0.5f*t0*(1.0f + erff(t0*0.70710678118654752f));
          t1 = 0.5f*t1*(1.0f + erff(t1*0.70710678118654752f));
          t2 = 0.5f*t2*(1.0f + erff(t2*0.70710678118654752f));
          t3 = 0.5f*t3*(1.0f + erff(t3*0.70710678118654752f));
          ushort4 u; u.x=f2bf(t0); u.y=f2bf(t1); u.z=f2bf(t2); u.w=f2bf(t3);
          *(ushort4*)&outb[(long)gm*N + gn] = u;
        } else if (EPI == 2){
          float4 bv = *(const float4*)&bias[gn];
          float4 t = *(float4*)&resid[(long)gm*N + gn];
          t.x += v.x + bv.x; t.y += v.y + bv.y; t.z += v.z + bv.z; t.w += v.w + bv.w;
          *(float4*)&resid[(long)gm*N + gn] = t;
        } else {  // EPI == 3
          float4 s4 = *(const float4*)&sc[gn];
          float4 h4 = *(const float4*)&sh[gn];
          v.x = v.x*s4.x + h4.x; v.y = v.y*s4.y + h4.y;
          v.z = v.z*s4.z + h4.z; v.w = v.w*s4.w + h4.w;
          *(float4*)&outf[(long)gm*N + gn] = v;
        }
      }
      __syncthreads();
    }
  }
}

// ---------------- LayerNorm over C=256 ----------------
__global__ __launch_bounds__(256) void ln_k(const float* __restrict__ X,
    const float* __restrict__ g, const float* __restrict__ b,
    float* __restrict__ outf, ushort* __restrict__ outb)
{
  const int wid = threadIdx.x>>6, lane = threadIdx.x&63;
  const long row = (long)blockIdx.x*4 + wid;
  const float4 v = *(const float4*)&X[row*256 + lane*4];
  float s = v.x+v.y+v.z+v.w;
  #pragma unroll
  for (int m=1;m<64;m<<=1) s += __shfl_xor(s, m);
  float mu = s * (1.0f/256.0f);
  float d0=v.x-mu, d1=v.y-mu, d2=v.z-mu, d3=v.w-mu;
  float q = d0*d0+d1*d1+d2*d2+d3*d3;
  #pragma unroll
  for (int m=1;m<64;m<<=1) q += __shfl_xor(q, m);
  float rs = rsqrtf(q*(1.0f/256.0f) + EPSV);
  int c = lane*4;
  float o0 = d0*rs*g[c+0] + b[c+0];
  float o1 = d1*rs*g[c+1] + b[c+1];
  float o2 = d2*rs*g[c+2] + b[c+2];
  float o3 = d3*rs*g[c+3] + b[c+3];
  if (outf){ float4 o = {o0,o1,o2,o3}; *(float4*)&outf[row*256 + c] = o; }
  if (outb){
    ushort4 u; u.x=f2bf(o0); u.y=f2bf(o1); u.z=f2bf(o2); u.w=f2bf(o3);
    *(ushort4*)&outb[row*256 + c] = u;
  }
}

// ---------------- stripe-window attention + LePE (swapped-QK^T, in-register P) ----------------
template<int BR>
__global__ __launch_bounds__(256) void attn_k(
    const ushort* __restrict__ QKVw, ushort* __restrict__ ATT,
    const float* __restrict__ lepe_w, const float* __restrict__ lepe_b, int layer)
{
  __shared__ ushort q_lds[128][36];
  __shared__ ushort k_lds[128][36];
  __shared__ ushort vT[32][132];
  __shared__ float wl[32][9];
  __shared__ float bl[32];
  const int tid = threadIdx.x, wid = tid>>6, lane = tid&63;
  const int b = blockIdx.y;
  const int w = blockIdx.x>>2, h = blockIdx.x&3;
  const int choff = BR*128 + h*32;
  const int l15 = lane&15, lg = lane>>4;

  const long rowbase = ((long)b*32 + w)*128;
  const ushort* qb = QKVw + (((long)(0*2+BR)*4 + h)*32768L + rowbase)*32;
  const ushort* kb = QKVw + (((long)(1*2+BR)*4 + h)*32768L + rowbase)*32;
  const ushort* vb = QKVw + (((long)(2*2+BR)*4 + h)*32768L + rowbase)*32;

  for (int e = tid; e < 512; e += 256){
    int row = e>>2, c4 = (e&3)*8;
    *(uint4*)&q_lds[row][c4] = *(const uint4*)(qb + (long)e*8);
    *(uint4*)&k_lds[row][c4] = *(const uint4*)(kb + (long)e*8);
    uint4 val = *(const uint4*)(vb + (long)e*8);
    const ushort* u = (const ushort*)&val;
    #pragma unroll
    for (int jj=0;jj<8;jj++) vT[c4+jj][row] = u[jj];
  }
  for (int e = tid; e < 288; e += 256){
    int d = e/9, tap = e%9;
    wl[d][tap] = lepe_w[((long)((layer*2+BR)*128 + h*32 + d))*9 + tap];
  }
  if (tid < 32) bl[tid] = lepe_b[(layer*2+BR)*128 + h*32 + tid];
  __syncthreads();

  const int wrow = wid*32;
  const float scale = 0.17677669529663689f;
  const int srcE = (lane & 15) | ((lane & 16) << 1);
  const int srcO = srcE + 16;
  const bool hi = (lane >= 32);

  #pragma unroll
  for (int mi=0; mi<2; mi++){
    s8v aq = *(const s8v*)&q_lds[wrow + mi*16 + l15][lg*8];
    f4v S[8];
    #pragma unroll
    for (int ni=0; ni<8; ni++){
      s8v bk = *(const s8v*)&k_lds[ni*16 + l15][lg*8];
      f4v z = {0.f,0.f,0.f,0.f};
      S[ni] = __builtin_amdgcn_mfma_f32_16x16x32_bf16(bk, aq, z, 0,0,0);
    }
    float mx = -1e30f;
    #pragma unroll
    for (int ni=0; ni<8; ni++)
      #pragma unroll
      for (int r=0;r<4;r++){ S[ni][r] *= scale; mx = fmaxf(mx, S[ni][r]); }
    mx = fmaxf(mx, __shfl_xor(mx, 16));
    mx = fmaxf(mx, __shfl_xor(mx, 32));
    float sum = 0.f;
    #pragma unroll
    for (int ni=0; ni<8; ni++)
      #pragma unroll
      for (int r=0;r<4;r++){ S[ni][r] = __expf(S[ni][r]-mx); sum += S[ni][r]; }
    sum += __shfl_xor(sum, 16);
    sum += __shfl_xor(sum, 32);
    const float inv = 1.0f / sum;
    unsigned int Alo[8], Ahi[8];
    #pragma unroll
    for (int ni=0; ni<8; ni++){
      Alo[ni] = (unsigned)f2bf(S[ni][0]*inv) | ((unsigned)f2bf(S[ni][1]*inv)<<16);
      Ahi[ni] = (unsigned)f2bf(S[ni][2]*inv) | ((unsigned)f2bf(S[ni][3]*inv)<<16);
    }
    f4v acc2[2] = {{0.f,0.f,0.f,0.f},{0.f,0.f,0.f,0.f}};
    #pragma unroll
    for (int ks=0; ks<4; ks++){
      unsigned e0 = (unsigned)__shfl((int)Alo[2*ks],   srcE);
      unsigned e1 = (unsigned)__shfl((int)Ahi[2*ks],   srcE);
      unsigned e2 = (unsigned)__shfl((int)Alo[2*ks+1], srcE);
      unsigned e3 = (unsigned)__shfl((int)Ahi[2*ks+1], srcE);
      unsigned o0 = (unsigned)__shfl((int)Alo[2*ks],   srcO);
      unsigned o1 = (unsigned)__shfl((int)Ahi[2*ks],   srcO);
      unsigned o2 = (unsigned)__shfl((int)Alo[2*ks+1], srcO);
      unsigned o3 = (unsigned)__shfl((int)Ahi[2*ks+1], srcO);
      union { unsigned u[4]; s8v v; } ap;
      ap.u[0] = hi?e2:e0; ap.u[1] = hi?e3:e1; ap.u[2] = hi?o2:o0; ap.u[3] = hi?o3:o1;
      #pragma unroll
      for (int di=0; di<2; di++){
        s8v bv = *(const s8v*)&vT[di*16 + l15][ks*32 + lg*8];
        acc2[di] = __builtin_amdgcn_mfma_f32_16x16x32_bf16(ap.v, bv, acc2[di], 0,0,0);
      }
    }
    #pragma unroll
    for (int di=0; di<2; di++)
      #pragma unroll
      for (int r=0;r<4;r++){
        int s = wrow + mi*16 + lg*4 + r;
        int d = di*16 + l15;
        float v = acc2[di][r] + bl[d];
        const int HsL = (BR==0)?64:2, WsL = (BR==0)?2:64;
        int hs, ws2;
        if (BR==0){ hs = s>>1; ws2 = s&1; }
        else      { hs = s>>6; ws2 = s&63; }
        #pragma unroll
        for (int a=-1;a<=1;a++)
          #pragma unroll
          for (int bb=-1;bb<=1;bb++){
            int h2 = hs+a, w2 = ws2+bb;
            if (h2>=0 && h2<HsL && w2>=0 && w2<WsL){
              int s2 = h2*WsL + w2;
              v += wl[d][(a+1)*3 + (bb+1)] * bf2f(vT[d][s2]);
            }
          }
        int y, x;
        if (BR==0){ y = s>>1; x = (w<<1)|(s&1); }
        else      { y = (w<<1)|(s>>6); x = s&63; }
        long tok = ((long)b*64 + y)*64 + x;
        ATT[tok*256 + choff + d] = f2bf(v);
      }
  }
}

// ---------------- final write: T [tok][256] f32 -> d_out f32 NCHW halves (LDS-tiled, coalesced) ----------------
__global__ __launch_bounds__(256) void write_out_k(const float* __restrict__ T, float* __restrict__ out){
  __shared__ float tile[64][133];
  const int y = blockIdx.x, b = blockIdx.y, half = blockIdx.z;
  const int tid = threadIdx.x;
  {
    const int c = tid & 127, xh = tid >> 7;
    #pragma unroll
    for (int i=0;i<32;i++){
      int x = i*2 + xh;
      tile[x][c] = T[(((long)b*64 + y)*64 + x)*256 + half*128 + c];
    }
  }
  __syncthreads();
  {
    const int x = tid & 63, ch = tid >> 6;
    float* op = out + (long)half*4194304 + (long)b*524288 + (long)y*64;
    #pragma unroll
    for (int i=0;i<32;i++){
      int c = i*4 + ch;
      op[(long)c*4096 + x] = tile[x][c];
    }
  }
}

extern "C" void kernel_launch(void* const* d_in, const int* in_sizes, int n_in,
                              void* d_out, int out_size, void* d_ws, size_t ws_size,
                              hipStream_t stream)
{
  (void)in_sizes; (void)n_in; (void)out_size;
  const float* x1     = (const float*)d_in[0];
  const float* x2     = (const float*)d_in[1];
  const float* conv_w = (const float*)d_in[2];
  const float* conv_b = (const float*)d_in[3];
  const float* bn_g   = (const float*)d_in[4];
  const float* bn_b   = (const float*)d_in[5];
  const float* bn_m   = (const float*)d_in[6];
  const float* bn_v   = (const float*)d_in[7];
  const float* ln0_g  = (const float*)d_in[8];
  const float* ln0_b  = (const float*)d_in[9];
  const float* n1_g   = (const float*)d_in[10];
  const float* n1_b   = (const float*)d_in[11];
  const float* qkv_w  = (const float*)d_in[12];
  const float* lepe_w = (const float*)d_in[13];
  const float* lepe_b = (const float*)d_in[14];
  const float* proj_w = (const float*)d_in[15];
  const float* proj_b = (const float*)d_in[16];
  const float* n2_g   = (const float*)d_in[17];
  const float* n2_b   = (const float*)d_in[18];
  const float* fc1_w  = (const float*)d_in[19];
  const float* fc1_b  = (const float*)d_in[20];
  const float* fc2_w  = (const float*)d_in[21];
  const float* fc2_b  = (const float*)d_in[22];

  if (ws_size < 121767936ULL){
    hipMemsetAsync(d_out, 0, (size_t)out_size*4, stream);
    return;
  }

  char* ws = (char*)d_ws;
  ushort* QKVb = (ushort*)ws;          // R1 (67.1MB): QKVw(50.3MB)/H1b(67.1MB)/TMPf(33.5MB) disjoint
  ushort* H1b  = (ushort*)ws;
  float*  TMPf = (float*)ws;
  size_t off = 67108864;
  float*  T    = (float*)(ws + off);
  ushort* Xin  = (ushort*)(ws + off);  // alias: Xin dead before T first written
  off += 33554432;
  ushort* Xb   = (ushort*)(ws + off);
  ushort* ATTb = (ushort*)(ws + off);  // alias: lifetimes interleave, never overlap
  off += 16777216;
  ushort* Wc   = (ushort*)(ws + off); off += 1179648;
  ushort* Wq   = (ushort*)(ws + off); off += 786432;
  ushort* Wp   = (ushort*)(ws + off); off += 262144;
  ushort* W1   = (ushort*)(ws + off); off += 1048576;
  ushort* W2   = (ushort*)(ws + off); off += 1048576;
  float*  scv  = (float*)(ws + off);  off += 1024;
  float*  shv  = (float*)(ws + off);  off += 1024;

  hipMemsetAsync(Xin, 0, (size_t)8*66*66*256*2, stream);
  repack_in_k<<<dim3(64,8), 256, 0, stream>>>(x1, x2, Xin);
  repack_convw_k<<<576, 256, 0, stream>>>(conv_w, Wc);
  for (int i=0;i<2;i++){
    transpose_w_k<<<512,256,0,stream>>>(qkv_w + (long)i*196608, Wq + (long)i*196608, 256, 768);
    transpose_w_k<<<128,256,0,stream>>>(proj_w + (long)i*65536, Wp + (long)i*65536, 256, 256);
    transpose_w_k<<<512,256,0,stream>>>(fc1_w + (long)i*262144, W1 + (long)i*262144, 256, 1024);
    transpose_w_k<<<512,256,0,stream>>>(fc2_w + (long)i*262144, W2 + (long)i*262144, 1024, 256);
  }
  bnprep_k<<<1,256,0,stream>>>(conv_b, bn_g, bn_b, bn_m, bn_v, scv, shv);

  // conv 3x3 + BN (implicit GEMM, K=2304) -> TMPf f32
  gemm_k<3,true><<<dim3(256,2),256,0,stream>>>(nullptr, Xin, Wc, nullptr, scv, shv,
                                               nullptr, nullptr, TMPf, 256, 2304);
  // LN0 -> T
  ln_k<<<8192,256,0,stream>>>(TMPf, ln0_g, ln0_b, T, nullptr);

  for (int i=0;i<2;i++){
    ln_k<<<8192,256,0,stream>>>(T, n1_g + i*256, n1_b + i*256, nullptr, Xb);
    gemm_k<4,false><<<dim3(256,6),256,0,stream>>>(Xb, nullptr, Wq + (long)i*196608, nullptr,
                                                  nullptr, nullptr, nullptr, QKVb, nullptr, 768, 256);
    attn_k<0><<<dim3(128,8),256,0,stream>>>(QKVb, ATTb, lepe_w, lepe_b, i);
    attn_k<1><<<dim3(128,8),256,0,stream>>>(QKVb, ATTb, lepe_w, lepe_b, i);
    gemm_k<2,false><<<dim3(256,2),256,0,stream>>>(ATTb, nullptr, Wp + (long)i*65536, proj_b + i*256,
                                                  nullptr, nullptr, T, nullptr, nullptr, 256, 256);
    ln_k<<<8192,256,0,stream>>>(T, n2_g + i*256, n2_b + i*256, nullptr, Xb);
    gemm_k<1,false><<<dim3(256,8),256,0,stream>>>(Xb, nullptr, W1 + (long)i*262144, fc1_b + i*1024,
                                                  nullptr, nullptr, nullptr, H1b, nullptr, 1024, 256);
    gemm_k<2,false><<<dim3(256,2),256,0,stream>>>(H1b, nullptr, W2 + (long)i*262144, fc2_b + i*256,
                                                  nullptr, nullptr, T, nullptr, nullptr, 256, 1024);
  }
  write_out_k<<<dim3(64,8,2),256,0,stream>>>(T, (float*)d_out);
}

// Round 14
// 511.426 us; speedup vs baseline: 1.2246x; 1.0553x over previous
//
#include <hip/hip_runtime.h>
#include <hip/hip_bf16.h>

#define EPSV 1e-5f

using s8v = __attribute__((ext_vector_type(8))) short;
using f4v = __attribute__((ext_vector_type(4))) float;

__device__ __forceinline__ float bf2f(ushort u){
  union { unsigned int i; float f; } x; x.i = ((unsigned int)u)<<16; return x.f;
}
__device__ __forceinline__ ushort f2bf(float f){
  union { float f; unsigned int i; } x; x.f = f;
  unsigned int r = x.i + 0x7FFFu + ((x.i>>16)&1u);
  return (ushort)(r>>16);
}
__device__ __forceinline__ float wsum(float s){
  #pragma unroll
  for (int m=1;m<64;m<<=1) s += __shfl_xor(s, m);
  return s;
}

__device__ __forceinline__ void gload16(const void* g, void* l){
  __builtin_amdgcn_global_load_lds((__attribute__((address_space(1))) void*)g,
                                   (__attribute__((address_space(3))) void*)l, 16, 0, 0);
}

// ---------------- input repack: NCHW f32 (x1|x2) -> padded NHWC bf16 [8][66][66][256] ----------------
__global__ __launch_bounds__(256) void repack_in_k(const float* __restrict__ x1,
                                                   const float* __restrict__ x2,
                                                   ushort* __restrict__ Xin){
  __shared__ ushort tile[256][66];
  const int y = blockIdx.x, b = blockIdx.y, tid = threadIdx.x;
  const int xl = tid & 63, cq = tid >> 6;
  for (int it=0; it<64; it++){
    int ci = it*4 + cq;
    float v;
    if (ci < 128) v = x1[(((long)b*128 + ci)*64 + y)*64 + xl];
    else          v = x2[(((long)b*128 + (ci-128))*64 + y)*64 + xl];
    tile[ci][xl] = f2bf(v);
  }
  __syncthreads();
  for (int x=0; x<64; x++){
    Xin[(((long)b*66 + (y+1))*66 + (x+1))*256 + tid] = tile[tid][x];
  }
}

// ---------------- conv weight repack: Wc[co][dd*256+ci] = w[co][ci][dd] ----------------
__global__ void repack_convw_k(const float* __restrict__ w, ushort* __restrict__ Wc){
  const long total = 256L*2304;
  for (long e = (long)blockIdx.x*blockDim.x + threadIdx.x; e < total; e += (long)gridDim.x*blockDim.x){
    int co = (int)(e / 2304), kk = (int)(e % 2304);
    int dd = kk >> 8, ci = kk & 255;
    Wc[e] = f2bf(w[((long)(co*256 + ci))*9 + dd]);
  }
}

// ---------------- weight transpose f32[K][N] -> bf16[N][K] ----------------
__global__ void transpose_w_k(const float* __restrict__ src, ushort* __restrict__ dst, int K, int N){
  long total = (long)K*N;
  for (long e = (long)blockIdx.x*blockDim.x + threadIdx.x; e < total; e += (long)gridDim.x*blockDim.x){
    int k = (int)(e / N), n = (int)(e % N);
    dst[(long)n*K + k] = f2bf(src[e]);
  }
}

__global__ void bnprep_k(const float* cb, const float* g, const float* b,
                         const float* m, const float* v, float* sc, float* sh){
  int n = threadIdx.x;
  if (n < 256){
    float s = g[n] * rsqrtf(v[n] + EPSV);
    sc[n] = s;
    sh[n] = (cb[n] - m[n])*s + b[n];
  }
}

// ================= fused full-row GEMM: BM=64, BN=N=256 =================
// EPI 0: conv (A from Xin via im2col) -> t=LN0(v*sc+sh) -> T ; Xb = LN_{g2,b2}(t)
// EPI 1: t = T + v + bias -> T ; Xb = LN_{g1,b1}(t)
// EPI 3: t = T + v + bias -> d_out direct NCHW (no T write)
template<int EPI>
__global__ __launch_bounds__(256) void gemm_f(
    const ushort* __restrict__ A, const ushort* __restrict__ Xin,
    const ushort* __restrict__ Wt, const float* __restrict__ bias,
    const float* __restrict__ sc, const float* __restrict__ sh,
    float* __restrict__ T, const float* __restrict__ g1, const float* __restrict__ b1,
    const float* __restrict__ g2, const float* __restrict__ b2,
    ushort* __restrict__ Xb, float* __restrict__ dout, int K)
{
  constexpr bool CONVA = (EPI==0);
  __shared__ ushort SMEM[32768];              // 64KB: staging 40KB / CT 64KB (disjoint phases)
  ushort* As = SMEM;                          // [64][64]
  ushort* Bs = SMEM + 4096;                   // [256][64]
  const int tid = threadIdx.x, wid = tid>>6, lane = tid&63;
  const int m0 = blockIdx.x*64;
  const int l15 = lane&15, lg = lane>>4;
  const int rS = wid*8 + (lane>>3);           // staging row within a 32-row pass
  const int cA = (lane&7)*8;

  const ushort* pA[2];
  if (CONVA){
    #pragma unroll
    for (int j=0;j<2;j++){
      int t = m0 + j*32 + rS;
      int b = t>>12, y = (t>>6)&63, x = t&63;
      pA[j] = Xin + ((long)((b*66 + y+1)*66) + (x+1))*256 + cA;
    }
  } else {
    #pragma unroll
    for (int j=0;j<2;j++) pA[j] = A + (long)(m0 + j*32 + rS)*K + cA;
  }
  const ushort* pB[8];
  #pragma unroll
  for (int j=0;j<8;j++) pB[j] = Wt + (long)(j*32 + rS)*K + cA;

  f4v acc[4][4] = {};

  for (int k0=0; k0<K; k0+=64){
    int koffA;
    if (CONVA){
      int dd = k0 >> 8;
      int dy = dd/3, dx = dd - dy*3;
      koffA = ((dy-1)*66 + (dx-1))*256 + (k0 & 255);
    } else koffA = k0;
    #pragma unroll
    for (int j=0;j<2;j++)
      gload16(pA[j] + koffA, (void*)&As[(j*256 + wid*64)*8]);
    #pragma unroll
    for (int j=0;j<8;j++)
      gload16(pB[j] + k0, (void*)&Bs[(j*256 + wid*64)*8]);
    __syncthreads();
    #pragma unroll
    for (int kk=0; kk<2; kk++){
      s8v a[4], b[4];
      const int ke = kk*32 + lg*8;
      #pragma unroll
      for (int mi=0;mi<4;mi++) a[mi] = *(const s8v*)&As[(mi*16 + l15)*64 + ke];
      #pragma unroll
      for (int ni=0;ni<4;ni++) b[ni] = *(const s8v*)&Bs[(wid*64 + ni*16 + l15)*64 + ke];
      #pragma unroll
      for (int mi=0;mi<4;mi++)
        #pragma unroll
        for (int ni=0;ni<4;ni++)
          acc[mi][ni] = __builtin_amdgcn_mfma_f32_16x16x32_bf16(a[mi], b[ni], acc[mi][ni], 0,0,0);
    }
    __syncthreads();
  }

  // ---- epilogue: CT[64][256] f32 in LDS, then per-row fused ops ----
  float* CT = (float*)SMEM;
  #pragma unroll
  for (int mi=0;mi<4;mi++)
    #pragma unroll
    for (int ni=0;ni<4;ni++)
      #pragma unroll
      for (int r=0;r<4;r++)
        CT[(mi*16 + lg*4 + r)*256 + wid*64 + ni*16 + l15] = acc[mi][ni][r];
  __syncthreads();

  const int c0 = lane*4;
  float4 scv4, shv4, bias4, g1v, b1v, g2v, b2v;
  if (EPI==0){
    scv4 = *(const float4*)&sc[c0]; shv4 = *(const float4*)&sh[c0];
    g1v = *(const float4*)&g1[c0];  b1v = *(const float4*)&b1[c0];
    g2v = *(const float4*)&g2[c0];  b2v = *(const float4*)&b2[c0];
  } else {
    bias4 = *(const float4*)&bias[c0];
    if (EPI==1){ g1v = *(const float4*)&g1[c0]; b1v = *(const float4*)&b1[c0]; }
  }

  for (int t=0; t<16; t++){
    const int r = wid*16 + t;
    const long gmr = m0 + r;
    float4 v = *(float4*)&CT[r*256 + c0];
    float4 t4;
    if (EPI==0){
      t4.x = v.x*scv4.x + shv4.x; t4.y = v.y*scv4.y + shv4.y;
      t4.z = v.z*scv4.z + shv4.z; t4.w = v.w*scv4.w + shv4.w;
    } else {
      float4 rv = *(float4*)&T[gmr*256 + c0];
      t4.x = rv.x + v.x + bias4.x; t4.y = rv.y + v.y + bias4.y;
      t4.z = rv.z + v.z + bias4.z; t4.w = rv.w + v.w + bias4.w;
    }
    if (EPI==3){
      *(float4*)&CT[r*256 + c0] = t4;       // stash for NCHW transpose pass
    } else {
      // first LN
      float mu = wsum(t4.x+t4.y+t4.z+t4.w) * (1.0f/256.0f);
      float d0=t4.x-mu, d1=t4.y-mu, d2=t4.z-mu, d3=t4.w-mu;
      float rs = rsqrtf(wsum(d0*d0+d1*d1+d2*d2+d3*d3)*(1.0f/256.0f) + EPSV);
      if (EPI==0){
        float u0 = d0*rs*g1v.x + b1v.x, u1 = d1*rs*g1v.y + b1v.y;
        float u2 = d2*rs*g1v.z + b1v.z, u3 = d3*rs*g1v.w + b1v.w;
        float4 u = {u0,u1,u2,u3};
        *(float4*)&T[gmr*256 + c0] = u;     // T = LN0 output (residual base)
        // second LN (n1 layer0)
        float mu2 = wsum(u0+u1+u2+u3) * (1.0f/256.0f);
        float e0=u0-mu2, e1=u1-mu2, e2=u2-mu2, e3=u3-mu2;
        float rs2 = rsqrtf(wsum(e0*e0+e1*e1+e2*e2+e3*e3)*(1.0f/256.0f) + EPSV);
        ushort4 o; o.x=f2bf(e0*rs2*g2v.x + b2v.x); o.y=f2bf(e1*rs2*g2v.y + b2v.y);
        o.z=f2bf(e2*rs2*g2v.z + b2v.z); o.w=f2bf(e3*rs2*g2v.w + b2v.w);
        *(ushort4*)&Xb[gmr*256 + c0] = o;
      } else {
        *(float4*)&T[gmr*256 + c0] = t4;    // residual stream update
        ushort4 o; o.x=f2bf(d0*rs*g1v.x + b1v.x); o.y=f2bf(d1*rs*g1v.y + b1v.y);
        o.z=f2bf(d2*rs*g1v.z + b1v.z); o.w=f2bf(d3*rs*g1v.w + b1v.w);
        *(ushort4*)&Xb[gmr*256 + c0] = o;
      }
    }
  }

  if (EPI==3){
    __syncthreads();
    const int b_ = m0>>12, y_ = (m0>>6)&63;
    float* obase = dout + (long)b_*524288 + (long)y_*64;
    for (int it=0; it<64; it++){
      int e = it*256 + tid;
      int c = e>>6, x = e&63;
      obase[(long)(c>>7)*4194304 + (long)(c&127)*4096 + x] = CT[x*256 + c];
    }
  }
}

// ---------------- generic MFMA GEMM (qkv N=768, fc1 N=1024) ----------------
// EPI: 1 bf16 bias+GELU; 4 qkv window-permuted bf16
#define BM 128
#define BN 128
#define BK 64
template<int EPI>
__global__ __launch_bounds__(256) void gemm_k(
    const ushort* __restrict__ A,
    const ushort* __restrict__ Wt, const float* __restrict__ bias,
    ushort* __restrict__ outb, int N, int K)
{
  __shared__ ushort SMEM[BM*BK + BN*BK];
  ushort* As = SMEM;
  ushort* Bs = SMEM + BM*BK;
  const int tid = threadIdx.x, wid = tid>>6, lane = tid&63;
  const int m0 = blockIdx.x*BM, n0 = blockIdx.y*BN;
  const int wm = (wid>>1)*64, wn = (wid&1)*64;
  const int l15 = lane&15, lg = lane>>4;

  const int rA = wid*32 + (lane>>3);
  const int cA = (lane&7)*8;
  const ushort* pA[4];
  #pragma unroll
  for (int j=0;j<4;j++) pA[j] = A + (long)(m0 + rA + j*8)*K + cA;
  const ushort* pB[4];
  #pragma unroll
  for (int j=0;j<4;j++) pB[j] = Wt + (long)(n0 + rA + j*8)*K + cA;

  f4v acc[4][4] = {};

  for (int k0=0; k0<K; k0+=BK){
    #pragma unroll
    for (int j=0;j<4;j++){
      gload16(pA[j] + k0, (void*)&As[(wid*32 + j*8)*BK]);
      gload16(pB[j] + k0, (void*)&Bs[(wid*32 + j*8)*BK]);
    }
    __syncthreads();
    #pragma unroll
    for (int kk=0; kk<2; kk++){
      s8v a[4], b[4];
      const int ke = kk*32 + lg*8;
      #pragma unroll
      for (int mi=0;mi<4;mi++) a[mi] = *(const s8v*)&As[(wm + mi*16 + l15)*BK + ke];
      #pragma unroll
      for (int ni=0;ni<4;ni++) b[ni] = *(const s8v*)&Bs[(wn + ni*16 + l15)*BK + ke];
      #pragma unroll
      for (int mi=0;mi<4;mi++)
        #pragma unroll
        for (int ni=0;ni<4;ni++)
          acc[mi][ni] = __builtin_amdgcn_mfma_f32_16x16x32_bf16(a[mi], b[ni], acc[mi][ni], 0,0,0);
    }
    __syncthreads();
  }

  if (EPI == 4){
    #pragma unroll
    for (int mi=0;mi<4;mi++)
      #pragma unroll
      for (int ni=0;ni<4;ni++)
        #pragma unroll
        for (int r=0;r<4;r++){
          int gm = m0 + wm + mi*16 + lg*4 + r;
          int gn = n0 + wn + ni*16 + l15;
          float v = acc[mi][ni][r];
          int tile = gn >> 8;
          int c = gn & 255;
          int br2 = (c >> 7) & 1;
          int hh = (c >> 5) & 3;
          int d = c & 31;
          int bb2 = gm >> 12;
          int y = (gm >> 6) & 63;
          int x = gm & 63;
          int wv, sv;
          if (br2 == 0){ wv = x >> 1; sv = (y << 1) | (x & 1); }
          else         { wv = y >> 1; sv = ((y & 1) << 6) | x; }
          long row = ((long)bb2*32 + wv)*128 + sv;
          outb[(((long)(tile*2 + br2)*4 + hh)*32768L + row)*32 + d] = f2bf(v);
        }
  } else {
    float* CT = (float*)SMEM;
    #pragma unroll
    for (int p=0; p<2; p++){
      if ((wid>>1) == p){
        #pragma unroll
        for (int mi=0;mi<4;mi++)
          #pragma unroll
          for (int ni=0;ni<4;ni++)
            #pragma unroll
            for (int r=0;r<4;r++)
              CT[(mi*16 + lg*4 + r)*128 + wn + ni*16 + l15] = acc[mi][ni][r];
      }
      __syncthreads();
      #pragma unroll
      for (int it=0; it<8; it++){
        int e = it*256 + tid;
        int row = e >> 5;
        int c4 = e & 31;
        float4 v = *(float4*)&CT[row*128 + c4*4];
        int gm = m0 + p*64 + row;
        int gn = n0 + c4*4;
        float4 bv = *(const float4*)&bias[gn];
        float t0 = v.x + bv.x, t1 = v.y + bv.y, t2 = v.z + bv.z, t3 = v.w + bv.w;
        t0 = 0.5f*t0*(1.0f + erff(t0*0.70710678118654752f));
        t1 = 0.5f*t1*(1.0f + erff(t1*0.70710678118654752f));
        t2 = 0.5f*t2*(1.0f + erff(t2*0.70710678118654752f));
        t3 = 0.5f*t3*(1.0f + erff(t3*0.70710678118654752f));
        ushort4 u; u.x=f2bf(t0); u.y=f2bf(t1); u.z=f2bf(t2); u.w=f2bf(t3);
        *(ushort4*)&outb[(long)gm*N + gn] = u;
      }
      __syncthreads();
    }
  }
}

// ---------------- stripe-window attention + LePE (swapped-QK^T, in-register P) ----------------
template<int BR>
__global__ __launch_bounds__(256) void attn_k(
    const ushort* __restrict__ QKVw, ushort* __restrict__ ATT,
    const float* __restrict__ lepe_w, const float* __restrict__ lepe_b, int layer)
{
  __shared__ ushort q_lds[128][36];
  __shared__ ushort k_lds[128][36];
  __shared__ ushort vT[32][132];
  __shared__ float wl[32][9];
  __shared__ float bl[32];
  const int tid = threadIdx.x, wid = tid>>6, lane = tid&63;
  const int b = blockIdx.y;
  const int w = blockIdx.x>>2, h = blockIdx.x&3;
  const int choff = BR*128 + h*32;
  const int l15 = lane&15, lg = lane>>4;

  const long rowbase = ((long)b*32 + w)*128;
  const ushort* qb = QKVw + (((long)(0*2+BR)*4 + h)*32768L + rowbase)*32;
  const ushort* kb = QKVw + (((long)(1*2+BR)*4 + h)*32768L + rowbase)*32;
  const ushort* vb = QKVw + (((long)(2*2+BR)*4 + h)*32768L + rowbase)*32;

  for (int e = tid; e < 512; e += 256){
    int row = e>>2, c4 = (e&3)*8;
    *(uint4*)&q_lds[row][c4] = *(const uint4*)(qb + (long)e*8);
    *(uint4*)&k_lds[row][c4] = *(const uint4*)(kb + (long)e*8);
    uint4 val = *(const uint4*)(vb + (long)e*8);
    const ushort* u = (const ushort*)&val;
    #pragma unroll
    for (int jj=0;jj<8;jj++) vT[c4+jj][row] = u[jj];
  }
  for (int e = tid; e < 288; e += 256){
    int d = e/9, tap = e%9;
    wl[d][tap] = lepe_w[((long)((layer*2+BR)*128 + h*32 + d))*9 + tap];
  }
  if (tid < 32) bl[tid] = lepe_b[(layer*2+BR)*128 + h*32 + tid];
  __syncthreads();

  const int wrow = wid*32;
  const float scale = 0.17677669529663689f;
  const int srcE = (lane & 15) | ((lane & 16) << 1);
  const int srcO = srcE + 16;
  const bool hi = (lane >= 32);

  #pragma unroll
  for (int mi=0; mi<2; mi++){
    s8v aq = *(const s8v*)&q_lds[wrow + mi*16 + l15][lg*8];
    f4v S[8];
    #pragma unroll
    for (int ni=0; ni<8; ni++){
      s8v bk = *(const s8v*)&k_lds[ni*16 + l15][lg*8];
      f4v z = {0.f,0.f,0.f,0.f};
      S[ni] = __builtin_amdgcn_mfma_f32_16x16x32_bf16(bk, aq, z, 0,0,0);
    }
    float mx = -1e30f;
    #pragma unroll
    for (int ni=0; ni<8; ni++)
      #pragma unroll
      for (int r=0;r<4;r++){ S[ni][r] *= scale; mx = fmaxf(mx, S[ni][r]); }
    mx = fmaxf(mx, __shfl_xor(mx, 16));
    mx = fmaxf(mx, __shfl_xor(mx, 32));
    float sum = 0.f;
    #pragma unroll
    for (int ni=0; ni<8; ni++)
      #pragma unroll
      for (int r=0;r<4;r++){ S[ni][r] = __expf(S[ni][r]-mx); sum += S[ni][r]; }
    sum += __shfl_xor(sum, 16);
    sum += __shfl_xor(sum, 32);
    const float inv = 1.0f / sum;
    unsigned int Alo[8], Ahi[8];
    #pragma unroll
    for (int ni=0; ni<8; ni++){
      Alo[ni] = (unsigned)f2bf(S[ni][0]*inv) | ((unsigned)f2bf(S[ni][1]*inv)<<16);
      Ahi[ni] = (unsigned)f2bf(S[ni][2]*inv) | ((unsigned)f2bf(S[ni][3]*inv)<<16);
    }
    f4v acc2[2] = {{0.f,0.f,0.f,0.f},{0.f,0.f,0.f,0.f}};
    #pragma unroll
    for (int ks=0; ks<4; ks++){
      unsigned e0 = (unsigned)__shfl((int)Alo[2*ks],   srcE);
      unsigned e1 = (unsigned)__shfl((int)Ahi[2*ks],   srcE);
      unsigned e2 = (unsigned)__shfl((int)Alo[2*ks+1], srcE);
      unsigned e3 = (unsigned)__shfl((int)Ahi[2*ks+1], srcE);
      unsigned o0 = (unsigned)__shfl((int)Alo[2*ks],   srcO);
      unsigned o1 = (unsigned)__shfl((int)Ahi[2*ks],   srcO);
      unsigned o2 = (unsigned)__shfl((int)Alo[2*ks+1], srcO);
      unsigned o3 = (unsigned)__shfl((int)Ahi[2*ks+1], srcO);
      union { unsigned u[4]; s8v v; } ap;
      ap.u[0] = hi?e2:e0; ap.u[1] = hi?e3:e1; ap.u[2] = hi?o2:o0; ap.u[3] = hi?o3:o1;
      #pragma unroll
      for (int di=0; di<2; di++){
        s8v bv = *(const s8v*)&vT[di*16 + l15][ks*32 + lg*8];
        acc2[di] = __builtin_amdgcn_mfma_f32_16x16x32_bf16(ap.v, bv, acc2[di], 0,0,0);
      }
    }
    #pragma unroll
    for (int di=0; di<2; di++)
      #pragma unroll
      for (int r=0;r<4;r++){
        int s = wrow + mi*16 + lg*4 + r;
        int d = di*16 + l15;
        float v = acc2[di][r] + bl[d];
        const int HsL = (BR==0)?64:2, WsL = (BR==0)?2:64;
        int hs, ws2;
        if (BR==0){ hs = s>>1; ws2 = s&1; }
        else      { hs = s>>6; ws2 = s&63; }
        #pragma unroll
        for (int a=-1;a<=1;a++)
          #pragma unroll
          for (int bb=-1;bb<=1;bb++){
            int h2 = hs+a, w2 = ws2+bb;
            if (h2>=0 && h2<HsL && w2>=0 && w2<WsL){
              int s2 = h2*WsL + w2;
              v += wl[d][(a+1)*3 + (bb+1)] * bf2f(vT[d][s2]);
            }
          }
        int y, x;
        if (BR==0){ y = s>>1; x = (w<<1)|(s&1); }
        else      { y = (w<<1)|(s>>6); x = s&63; }
        long tok = ((long)b*64 + y)*64 + x;
        ATT[tok*256 + choff + d] = f2bf(v);
      }
  }
}

extern "C" void kernel_launch(void* const* d_in, const int* in_sizes, int n_in,
                              void* d_out, int out_size, void* d_ws, size_t ws_size,
                              hipStream_t stream)
{
  (void)in_sizes; (void)n_in; (void)out_size;
  const float* x1     = (const float*)d_in[0];
  const float* x2     = (const float*)d_in[1];
  const float* conv_w = (const float*)d_in[2];
  const float* conv_b = (const float*)d_in[3];
  const float* bn_g   = (const float*)d_in[4];
  const float* bn_b   = (const float*)d_in[5];
  const float* bn_m   = (const float*)d_in[6];
  const float* bn_v   = (const float*)d_in[7];
  const float* ln0_g  = (const float*)d_in[8];
  const float* ln0_b  = (const float*)d_in[9];
  const float* n1_g   = (const float*)d_in[10];
  const float* n1_b   = (const float*)d_in[11];
  const float* qkv_w  = (const float*)d_in[12];
  const float* lepe_w = (const float*)d_in[13];
  const float* lepe_b = (const float*)d_in[14];
  const float* proj_w = (const float*)d_in[15];
  const float* proj_b = (const float*)d_in[16];
  const float* n2_g   = (const float*)d_in[17];
  const float* n2_b   = (const float*)d_in[18];
  const float* fc1_w  = (const float*)d_in[19];
  const float* fc1_b  = (const float*)d_in[20];
  const float* fc2_w  = (const float*)d_in[21];
  const float* fc2_b  = (const float*)d_in[22];

  if (ws_size < 121767936ULL){
    hipMemsetAsync(d_out, 0, (size_t)out_size*4, stream);
    return;
  }

  // ---- workspace layout (NO aliased in-place read/write anywhere) ----
  // R1 [0, 67.11MB): Xin (conv input, 17.8MB) / QKVb (50.33MB) / H1b (67.11MB) — disjoint lifetimes
  // ATTb [50.33, 67.11MB): attn output — QKVb ends at 50.33MB, so attn (reads QKVb, writes ATTb)
  //   and proj (reads ATTb, writes Xb at 100.66MB) never touch the same region.
  char* ws = (char*)d_ws;
  ushort* Xin  = (ushort*)ws;
  ushort* QKVb = (ushort*)ws;
  ushort* H1b  = (ushort*)ws;
  ushort* ATTb = (ushort*)(ws + 50331648);
  float*  T    = (float*)(ws + 67108864);
  ushort* Xb   = (ushort*)(ws + 100663296);
  size_t off = 117440512;
  ushort* Wc   = (ushort*)(ws + off); off += 1179648;
  ushort* Wq   = (ushort*)(ws + off); off += 786432;
  ushort* Wp   = (ushort*)(ws + off); off += 262144;
  ushort* W1   = (ushort*)(ws + off); off += 1048576;
  ushort* W2   = (ushort*)(ws + off); off += 1048576;
  float*  scv  = (float*)(ws + off);  off += 1024;
  float*  shv  = (float*)(ws + off);  off += 1024;

  hipMemsetAsync(Xin, 0, (size_t)8*66*66*256*2, stream);
  repack_in_k<<<dim3(64,8), 256, 0, stream>>>(x1, x2, Xin);
  repack_convw_k<<<576, 256, 0, stream>>>(conv_w, Wc);
  for (int i=0;i<2;i++){
    transpose_w_k<<<512,256,0,stream>>>(qkv_w + (long)i*196608, Wq + (long)i*196608, 256, 768);
    transpose_w_k<<<128,256,0,stream>>>(proj_w + (long)i*65536, Wp + (long)i*65536, 256, 256);
    transpose_w_k<<<512,256,0,stream>>>(fc1_w + (long)i*262144, W1 + (long)i*262144, 256, 1024);
    transpose_w_k<<<512,256,0,stream>>>(fc2_w + (long)i*262144, W2 + (long)i*262144, 1024, 256);
  }
  bnprep_k<<<1,256,0,stream>>>(conv_b, bn_g, bn_b, bn_m, bn_v, scv, shv);

  // fused conv+BN+LN0+n1(layer0): -> T (f32 residual base), Xb (bf16 LN'd input to qkv)
  gemm_f<0><<<512,256,0,stream>>>(nullptr, Xin, Wc, nullptr, scv, shv,
                                  T, ln0_g, ln0_b, n1_g, n1_b, Xb, nullptr, 2304);

  for (int i=0;i<2;i++){
    gemm_k<4><<<dim3(256,6),256,0,stream>>>(Xb, Wq + (long)i*196608, nullptr, QKVb, 768, 256);
    attn_k<0><<<dim3(128,8),256,0,stream>>>(QKVb, ATTb, lepe_w, lepe_b, i);
    attn_k<1><<<dim3(128,8),256,0,stream>>>(QKVb, ATTb, lepe_w, lepe_b, i);
    // proj + residual + n2-LN -> T, Xb   (ATTb and Xb now DISJOINT)
    gemm_f<1><<<512,256,0,stream>>>(ATTb, nullptr, Wp + (long)i*65536, proj_b + i*256,
                                    nullptr, nullptr, T, n2_g + i*256, n2_b + i*256,
                                    nullptr, nullptr, Xb, nullptr, 256);
    gemm_k<1><<<dim3(256,8),256,0,stream>>>(Xb, W1 + (long)i*262144, fc1_b + i*1024, H1b, 1024, 256);
    if (i == 0){
      gemm_f<1><<<512,256,0,stream>>>(H1b, nullptr, W2, fc2_b,
                                      nullptr, nullptr, T, n1_g + 256, n1_b + 256,
                                      nullptr, nullptr, Xb, nullptr, 1024);
    } else {
      gemm_f<3><<<512,256,0,stream>>>(H1b, nullptr, W2 + 262144, fc2_b + 256,
                                      nullptr, nullptr, T, nullptr, nullptr,
                                      nullptr, nullptr, nullptr, (float*)d_out, 1024);
    }
  }
}

// Round 15
// 486.487 us; speedup vs baseline: 1.2873x; 1.0513x over previous
//
#include <hip/hip_runtime.h>
#include <hip/hip_bf16.h>

#define EPSV 1e-5f

using s8v = __attribute__((ext_vector_type(8))) short;
using f4v = __attribute__((ext_vector_type(4))) float;

__device__ __forceinline__ float bf2f(ushort u){
  union { unsigned int i; float f; } x; x.i = ((unsigned int)u)<<16; return x.f;
}
__device__ __forceinline__ ushort f2bf(float f){
  union { float f; unsigned int i; } x; x.f = f;
  unsigned int r = x.i + 0x7FFFu + ((x.i>>16)&1u);
  return (ushort)(r>>16);
}
__device__ __forceinline__ float wsum(float s){
  #pragma unroll
  for (int m=1;m<64;m<<=1) s += __shfl_xor(s, m);
  return s;
}

__device__ __forceinline__ void gload16(const void* g, void* l){
  __builtin_amdgcn_global_load_lds((__attribute__((address_space(1))) void*)g,
                                   (__attribute__((address_space(3))) void*)l, 16, 0, 0);
}

// ---------------- input repack: NCHW f32 (x1|x2) -> padded NHWC bf16 [8][66][66][256] ----------------
__global__ __launch_bounds__(256) void repack_in_k(const float* __restrict__ x1,
                                                   const float* __restrict__ x2,
                                                   ushort* __restrict__ Xin){
  __shared__ ushort tile[256][66];
  const int y = blockIdx.x, b = blockIdx.y, tid = threadIdx.x;
  const int xl = tid & 63, cq = tid >> 6;
  for (int it=0; it<64; it++){
    int ci = it*4 + cq;
    float v;
    if (ci < 128) v = x1[(((long)b*128 + ci)*64 + y)*64 + xl];
    else          v = x2[(((long)b*128 + (ci-128))*64 + y)*64 + xl];
    tile[ci][xl] = f2bf(v);
  }
  __syncthreads();
  for (int x=0; x<64; x++){
    Xin[(((long)b*66 + (y+1))*66 + (x+1))*256 + tid] = tile[tid][x];
  }
}

// ---------------- conv weight repack: Wc[co][dd*256+ci] = w[co][ci][dd] ----------------
__global__ void repack_convw_k(const float* __restrict__ w, ushort* __restrict__ Wc){
  const long total = 256L*2304;
  for (long e = (long)blockIdx.x*blockDim.x + threadIdx.x; e < total; e += (long)gridDim.x*blockDim.x){
    int co = (int)(e / 2304), kk = (int)(e % 2304);
    int dd = kk >> 8, ci = kk & 255;
    Wc[e] = f2bf(w[((long)(co*256 + ci))*9 + dd]);
  }
}

// ---------------- weight transpose f32[K][N] -> bf16[N][K] ----------------
__global__ void transpose_w_k(const float* __restrict__ src, ushort* __restrict__ dst, int K, int N){
  long total = (long)K*N;
  for (long e = (long)blockIdx.x*blockDim.x + threadIdx.x; e < total; e += (long)gridDim.x*blockDim.x){
    int k = (int)(e / N), n = (int)(e % N);
    dst[(long)n*K + k] = f2bf(src[e]);
  }
}

__global__ void bnprep_k(const float* cb, const float* g, const float* b,
                         const float* m, const float* v, float* sc, float* sh){
  int n = threadIdx.x;
  if (n < 256){
    float s = g[n] * rsqrtf(v[n] + EPSV);
    sc[n] = s;
    sh[n] = (cb[n] - m[n])*s + b[n];
  }
}

// ================= fused full-row GEMM: BM=64, BN=N=256, double-buffered + swizzled =================
// EPI 0: conv (A from Xin via im2col) -> t=LN0(v*sc+sh) -> T ; Xb = LN_{g2,b2}(t)
// EPI 1: t = T + v + bias -> T ; Xb = LN_{g1,b1}(t)
// EPI 3: t = T + v + bias -> d_out direct NCHW (no T write)
// LDS layout swizzle (both-sides): staged row r holds global 16B-chunk j at chunk j^(r&7);
// staging achieves this by pre-swizzling the per-lane GLOBAL column (dest stays linear).
template<int EPI>
__global__ __launch_bounds__(256) void gemm_f(
    const ushort* __restrict__ A, const ushort* __restrict__ Xin,
    const ushort* __restrict__ Wt, const float* __restrict__ bias,
    const float* __restrict__ sc, const float* __restrict__ sh,
    float* __restrict__ T, const float* __restrict__ g1, const float* __restrict__ b1,
    const float* __restrict__ g2, const float* __restrict__ b2,
    ushort* __restrict__ Xb, float* __restrict__ dout, int K)
{
  constexpr bool CONVA = (EPI==0);
  __shared__ ushort SMEM[40960];              // 80KB: 2 x (As 8KB + Bs 32KB); CT 64KB aliases later
  const int tid = threadIdx.x, wid = tid>>6, lane = tid&63;
  const int m0 = blockIdx.x*64;
  const int l15 = lane&15, lg = lane>>4;
  const int rS = wid*8 + (lane>>3);           // staging row within a 32-row pass
  const int cS = (((lane&7) ^ (lane>>3))*8);  // pre-swizzled global col (ushort units)

  const ushort* pA[2];
  if (CONVA){
    #pragma unroll
    for (int j=0;j<2;j++){
      int t = m0 + j*32 + rS;
      int b = t>>12, y = (t>>6)&63, x = t&63;
      pA[j] = Xin + ((long)((b*66 + y+1)*66) + (x+1))*256 + cS;
    }
  } else {
    #pragma unroll
    for (int j=0;j<2;j++) pA[j] = A + (long)(m0 + j*32 + rS)*K + cS;
  }
  const ushort* pB[8];
  #pragma unroll
  for (int j=0;j<8;j++) pB[j] = Wt + (long)(j*32 + rS)*K + cS;

  auto stage = [&](int buf, int k0){
    ushort* AsB = SMEM + buf*20480;
    ushort* BsB = AsB + 4096;
    int koffA;
    if (CONVA){
      int dd = k0 >> 8;
      int dy = dd/3, dx = dd - dy*3;
      koffA = ((dy-1)*66 + (dx-1))*256 + (k0 & 255);
    } else koffA = k0;
    #pragma unroll
    for (int j=0;j<2;j++)
      gload16(pA[j] + koffA, (void*)&AsB[(j*256 + wid*64)*8]);
    #pragma unroll
    for (int j=0;j<8;j++)
      gload16(pB[j] + k0, (void*)&BsB[(j*256 + wid*64)*8]);
  };

  f4v acc[4][4] = {};

  int cur = 0;
  stage(0, 0);
  __syncthreads();
  for (int k0=0; k0<K; k0+=64){
    if (k0 + 64 < K) stage(cur^1, k0 + 64);   // prefetch next tile into other buffer
    const ushort* AsB = SMEM + cur*20480;
    const ushort* BsB = AsB + 4096;
    #pragma unroll
    for (int kk=0; kk<2; kk++){
      s8v a[4], b[4];
      const int kch = ((kk*4 + lg) ^ (l15 & 7))*8;   // swizzled chunk read
      #pragma unroll
      for (int mi=0;mi<4;mi++) a[mi] = *(const s8v*)&AsB[(mi*16 + l15)*64 + kch];
      #pragma unroll
      for (int ni=0;ni<4;ni++) b[ni] = *(const s8v*)&BsB[(wid*64 + ni*16 + l15)*64 + kch];
      #pragma unroll
      for (int mi=0;mi<4;mi++)
        #pragma unroll
        for (int ni=0;ni<4;ni++)
          acc[mi][ni] = __builtin_amdgcn_mfma_f32_16x16x32_bf16(a[mi], b[ni], acc[mi][ni], 0,0,0);
    }
    __syncthreads();   // drains prefetch vmcnt + protects buffer swap
    cur ^= 1;
  }

  // ---- epilogue: CT[64][256] f32 in LDS, then per-row fused ops ----
  float* CT = (float*)SMEM;
  #pragma unroll
  for (int mi=0;mi<4;mi++)
    #pragma unroll
    for (int ni=0;ni<4;ni++)
      #pragma unroll
      for (int r=0;r<4;r++)
        CT[(mi*16 + lg*4 + r)*256 + wid*64 + ni*16 + l15] = acc[mi][ni][r];
  __syncthreads();

  const int c0 = lane*4;
  float4 scv4, shv4, bias4, g1v, b1v, g2v, b2v;
  if (EPI==0){
    scv4 = *(const float4*)&sc[c0]; shv4 = *(const float4*)&sh[c0];
    g1v = *(const float4*)&g1[c0];  b1v = *(const float4*)&b1[c0];
    g2v = *(const float4*)&g2[c0];  b2v = *(const float4*)&b2[c0];
  } else {
    bias4 = *(const float4*)&bias[c0];
    if (EPI==1){ g1v = *(const float4*)&g1[c0]; b1v = *(const float4*)&b1[c0]; }
  }

  for (int t=0; t<16; t++){
    const int r = wid*16 + t;
    const long gmr = m0 + r;
    float4 v = *(float4*)&CT[r*256 + c0];
    float4 t4;
    if (EPI==0){
      t4.x = v.x*scv4.x + shv4.x; t4.y = v.y*scv4.y + shv4.y;
      t4.z = v.z*scv4.z + shv4.z; t4.w = v.w*scv4.w + shv4.w;
    } else {
      float4 rv = *(float4*)&T[gmr*256 + c0];
      t4.x = rv.x + v.x + bias4.x; t4.y = rv.y + v.y + bias4.y;
      t4.z = rv.z + v.z + bias4.z; t4.w = rv.w + v.w + bias4.w;
    }
    if (EPI==3){
      *(float4*)&CT[r*256 + c0] = t4;       // stash for NCHW transpose pass
    } else {
      float mu = wsum(t4.x+t4.y+t4.z+t4.w) * (1.0f/256.0f);
      float d0=t4.x-mu, d1=t4.y-mu, d2=t4.z-mu, d3=t4.w-mu;
      float rs = rsqrtf(wsum(d0*d0+d1*d1+d2*d2+d3*d3)*(1.0f/256.0f) + EPSV);
      if (EPI==0){
        float u0 = d0*rs*g1v.x + b1v.x, u1 = d1*rs*g1v.y + b1v.y;
        float u2 = d2*rs*g1v.z + b1v.z, u3 = d3*rs*g1v.w + b1v.w;
        float4 u = {u0,u1,u2,u3};
        *(float4*)&T[gmr*256 + c0] = u;
        float mu2 = wsum(u0+u1+u2+u3) * (1.0f/256.0f);
        float e0=u0-mu2, e1=u1-mu2, e2=u2-mu2, e3=u3-mu2;
        float rs2 = rsqrtf(wsum(e0*e0+e1*e1+e2*e2+e3*e3)*(1.0f/256.0f) + EPSV);
        ushort4 o; o.x=f2bf(e0*rs2*g2v.x + b2v.x); o.y=f2bf(e1*rs2*g2v.y + b2v.y);
        o.z=f2bf(e2*rs2*g2v.z + b2v.z); o.w=f2bf(e3*rs2*g2v.w + b2v.w);
        *(ushort4*)&Xb[gmr*256 + c0] = o;
      } else {
        *(float4*)&T[gmr*256 + c0] = t4;
        ushort4 o; o.x=f2bf(d0*rs*g1v.x + b1v.x); o.y=f2bf(d1*rs*g1v.y + b1v.y);
        o.z=f2bf(d2*rs*g1v.z + b1v.z); o.w=f2bf(d3*rs*g1v.w + b1v.w);
        *(ushort4*)&Xb[gmr*256 + c0] = o;
      }
    }
  }

  if (EPI==3){
    __syncthreads();
    const int b_ = m0>>12, y_ = (m0>>6)&63;
    float* obase = dout + (long)b_*524288 + (long)y_*64;
    for (int it=0; it<64; it++){
      int e = it*256 + tid;
      int c = e>>6, x = e&63;
      obase[(long)(c>>7)*4194304 + (long)(c&127)*4096 + x] = CT[x*256 + c];
    }
  }
}

// ---------------- generic MFMA GEMM (qkv N=768, fc1 N=1024) — swizzled LDS, single-buffer ----------------
// EPI: 1 bf16 bias+GELU; 4 qkv window-permuted bf16
#define BM 128
#define BN 128
#define BK 64
template<int EPI>
__global__ __launch_bounds__(256) void gemm_k(
    const ushort* __restrict__ A,
    const ushort* __restrict__ Wt, const float* __restrict__ bias,
    ushort* __restrict__ outb, int N, int K)
{
  __shared__ ushort SMEM[BM*BK + BN*BK];
  ushort* As = SMEM;
  ushort* Bs = SMEM + BM*BK;
  const int tid = threadIdx.x, wid = tid>>6, lane = tid&63;
  const int m0 = blockIdx.x*BM, n0 = blockIdx.y*BN;
  const int wm = (wid>>1)*64, wn = (wid&1)*64;
  const int l15 = lane&15, lg = lane>>4;

  const int rA = wid*32 + (lane>>3);
  const int cS = (((lane&7) ^ (lane>>3))*8);  // pre-swizzled global col
  const ushort* pA[4];
  #pragma unroll
  for (int j=0;j<4;j++) pA[j] = A + (long)(m0 + rA + j*8)*K + cS;
  const ushort* pB[4];
  #pragma unroll
  for (int j=0;j<4;j++) pB[j] = Wt + (long)(n0 + rA + j*8)*K + cS;

  f4v acc[4][4] = {};

  for (int k0=0; k0<K; k0+=BK){
    #pragma unroll
    for (int j=0;j<4;j++){
      gload16(pA[j] + k0, (void*)&As[(wid*32 + j*8)*BK]);
      gload16(pB[j] + k0, (void*)&Bs[(wid*32 + j*8)*BK]);
    }
    __syncthreads();
    #pragma unroll
    for (int kk=0; kk<2; kk++){
      s8v a[4], b[4];
      const int kch = ((kk*4 + lg) ^ (l15 & 7))*8;
      #pragma unroll
      for (int mi=0;mi<4;mi++) a[mi] = *(const s8v*)&As[(wm + mi*16 + l15)*BK + kch];
      #pragma unroll
      for (int ni=0;ni<4;ni++) b[ni] = *(const s8v*)&Bs[(wn + ni*16 + l15)*BK + kch];
      #pragma unroll
      for (int mi=0;mi<4;mi++)
        #pragma unroll
        for (int ni=0;ni<4;ni++)
          acc[mi][ni] = __builtin_amdgcn_mfma_f32_16x16x32_bf16(a[mi], b[ni], acc[mi][ni], 0,0,0);
    }
    __syncthreads();
  }

  if (EPI == 4){
    #pragma unroll
    for (int mi=0;mi<4;mi++)
      #pragma unroll
      for (int ni=0;ni<4;ni++)
        #pragma unroll
        for (int r=0;r<4;r++){
          int gm = m0 + wm + mi*16 + lg*4 + r;
          int gn = n0 + wn + ni*16 + l15;
          float v = acc[mi][ni][r];
          int tile = gn >> 8;
          int c = gn & 255;
          int br2 = (c >> 7) & 1;
          int hh = (c >> 5) & 3;
          int d = c & 31;
          int bb2 = gm >> 12;
          int y = (gm >> 6) & 63;
          int x = gm & 63;
          int wv, sv;
          if (br2 == 0){ wv = x >> 1; sv = (y << 1) | (x & 1); }
          else         { wv = y >> 1; sv = ((y & 1) << 6) | x; }
          long row = ((long)bb2*32 + wv)*128 + sv;
          outb[(((long)(tile*2 + br2)*4 + hh)*32768L + row)*32 + d] = f2bf(v);
        }
  } else {
    float* CT = (float*)SMEM;
    #pragma unroll
    for (int p=0; p<2; p++){
      if ((wid>>1) == p){
        #pragma unroll
        for (int mi=0;mi<4;mi++)
          #pragma unroll
          for (int ni=0;ni<4;ni++)
            #pragma unroll
            for (int r=0;r<4;r++)
              CT[(mi*16 + lg*4 + r)*128 + wn + ni*16 + l15] = acc[mi][ni][r];
      }
      __syncthreads();
      #pragma unroll
      for (int it=0; it<8; it++){
        int e = it*256 + tid;
        int row = e >> 5;
        int c4 = e & 31;
        float4 v = *(float4*)&CT[row*128 + c4*4];
        int gm = m0 + p*64 + row;
        int gn = n0 + c4*4;
        float4 bv = *(const float4*)&bias[gn];
        float t0 = v.x + bv.x, t1 = v.y + bv.y, t2 = v.z + bv.z, t3 = v.w + bv.w;
        t0 = 0.5f*t0*(1.0f + erff(t0*0.70710678118654752f));
        t1 = 0.5f*t1*(1.0f + erff(t1*0.70710678118654752f));
        t2 = 0.5f*t2*(1.0f + erff(t2*0.70710678118654752f));
        t3 = 0.5f*t3*(1.0f + erff(t3*0.70710678118654752f));
        ushort4 u; u.x=f2bf(t0); u.y=f2bf(t1); u.z=f2bf(t2); u.w=f2bf(t3);
        *(ushort4*)&outb[(long)gm*N + gn] = u;
      }
      __syncthreads();
    }
  }
}

// ---------------- stripe-window attention + LePE (swapped-QK^T, in-register P) ----------------
template<int BR>
__global__ __launch_bounds__(256) void attn_k(
    const ushort* __restrict__ QKVw, ushort* __restrict__ ATT,
    const float* __restrict__ lepe_w, const float* __restrict__ lepe_b, int layer)
{
  __shared__ ushort q_lds[128][36];
  __shared__ ushort k_lds[128][36];
  __shared__ ushort vT[32][132];
  __shared__ float wl[32][9];
  __shared__ float bl[32];
  const int tid = threadIdx.x, wid = tid>>6, lane = tid&63;
  const int b = blockIdx.y;
  const int w = blockIdx.x>>2, h = blockIdx.x&3;
  const int choff = BR*128 + h*32;
  const int l15 = lane&15, lg = lane>>4;

  const long rowbase = ((long)b*32 + w)*128;
  const ushort* qb = QKVw + (((long)(0*2+BR)*4 + h)*32768L + rowbase)*32;
  const ushort* kb = QKVw + (((long)(1*2+BR)*4 + h)*32768L + rowbase)*32;
  const ushort* vb = QKVw + (((long)(2*2+BR)*4 + h)*32768L + rowbase)*32;

  for (int e = tid; e < 512; e += 256){
    int row = e>>2, c4 = (e&3)*8;
    *(uint4*)&q_lds[row][c4] = *(const uint4*)(qb + (long)e*8);
    *(uint4*)&k_lds[row][c4] = *(const uint4*)(kb + (long)e*8);
    uint4 val = *(const uint4*)(vb + (long)e*8);
    const ushort* u = (const ushort*)&val;
    #pragma unroll
    for (int jj=0;jj<8;jj++) vT[c4+jj][row] = u[jj];
  }
  for (int e = tid; e < 288; e += 256){
    int d = e/9, tap = e%9;
    wl[d][tap] = lepe_w[((long)((layer*2+BR)*128 + h*32 + d))*9 + tap];
  }
  if (tid < 32) bl[tid] = lepe_b[(layer*2+BR)*128 + h*32 + tid];
  __syncthreads();

  const int wrow = wid*32;
  const float scale = 0.17677669529663689f;
  const int srcE = (lane & 15) | ((lane & 16) << 1);
  const int srcO = srcE + 16;
  const bool hi = (lane >= 32);

  #pragma unroll
  for (int mi=0; mi<2; mi++){
    s8v aq = *(const s8v*)&q_lds[wrow + mi*16 + l15][lg*8];
    f4v S[8];
    #pragma unroll
    for (int ni=0; ni<8; ni++){
      s8v bk = *(const s8v*)&k_lds[ni*16 + l15][lg*8];
      f4v z = {0.f,0.f,0.f,0.f};
      S[ni] = __builtin_amdgcn_mfma_f32_16x16x32_bf16(bk, aq, z, 0,0,0);
    }
    float mx = -1e30f;
    #pragma unroll
    for (int ni=0; ni<8; ni++)
      #pragma unroll
      for (int r=0;r<4;r++){ S[ni][r] *= scale; mx = fmaxf(mx, S[ni][r]); }
    mx = fmaxf(mx, __shfl_xor(mx, 16));
    mx = fmaxf(mx, __shfl_xor(mx, 32));
    float sum = 0.f;
    #pragma unroll
    for (int ni=0; ni<8; ni++)
      #pragma unroll
      for (int r=0;r<4;r++){ S[ni][r] = __expf(S[ni][r]-mx); sum += S[ni][r]; }
    sum += __shfl_xor(sum, 16);
    sum += __shfl_xor(sum, 32);
    const float inv = 1.0f / sum;
    unsigned int Alo[8], Ahi[8];
    #pragma unroll
    for (int ni=0; ni<8; ni++){
      Alo[ni] = (unsigned)f2bf(S[ni][0]*inv) | ((unsigned)f2bf(S[ni][1]*inv)<<16);
      Ahi[ni] = (unsigned)f2bf(S[ni][2]*inv) | ((unsigned)f2bf(S[ni][3]*inv)<<16);
    }
    f4v acc2[2] = {{0.f,0.f,0.f,0.f},{0.f,0.f,0.f,0.f}};
    #pragma unroll
    for (int ks=0; ks<4; ks++){
      unsigned e0 = (unsigned)__shfl((int)Alo[2*ks],   srcE);
      unsigned e1 = (unsigned)__shfl((int)Ahi[2*ks],   srcE);
      unsigned e2 = (unsigned)__shfl((int)Alo[2*ks+1], srcE);
      unsigned e3 = (unsigned)__shfl((int)Ahi[2*ks+1], srcE);
      unsigned o0 = (unsigned)__shfl((int)Alo[2*ks],   srcO);
      unsigned o1 = (unsigned)__shfl((int)Ahi[2*ks],   srcO);
      unsigned o2 = (unsigned)__shfl((int)Alo[2*ks+1], srcO);
      unsigned o3 = (unsigned)__shfl((int)Ahi[2*ks+1], srcO);
      union { unsigned u[4]; s8v v; } ap;
      ap.u[0] = hi?e2:e0; ap.u[1] = hi?e3:e1; ap.u[2] = hi?o2:o0; ap.u[3] = hi?o3:o1;
      #pragma unroll
      for (int di=0; di<2; di++){
        s8v bv = *(const s8v*)&vT[di*16 + l15][ks*32 + lg*8];
        acc2[di] = __builtin_amdgcn_mfma_f32_16x16x32_bf16(ap.v, bv, acc2[di], 0,0,0);
      }
    }
    #pragma unroll
    for (int di=0; di<2; di++)
      #pragma unroll
      for (int r=0;r<4;r++){
        int s = wrow + mi*16 + lg*4 + r;
        int d = di*16 + l15;
        float v = acc2[di][r] + bl[d];
        const int HsL = (BR==0)?64:2, WsL = (BR==0)?2:64;
        int hs, ws2;
        if (BR==0){ hs = s>>1; ws2 = s&1; }
        else      { hs = s>>6; ws2 = s&63; }
        #pragma unroll
        for (int a=-1;a<=1;a++)
          #pragma unroll
          for (int bb=-1;bb<=1;bb++){
            int h2 = hs+a, w2 = ws2+bb;
            if (h2>=0 && h2<HsL && w2>=0 && w2<WsL){
              int s2 = h2*WsL + w2;
              v += wl[d][(a+1)*3 + (bb+1)] * bf2f(vT[d][s2]);
            }
          }
        int y, x;
        if (BR==0){ y = s>>1; x = (w<<1)|(s&1); }
        else      { y = (w<<1)|(s>>6); x = s&63; }
        long tok = ((long)b*64 + y)*64 + x;
        ATT[tok*256 + choff + d] = f2bf(v);
      }
  }
}

extern "C" void kernel_launch(void* const* d_in, const int* in_sizes, int n_in,
                              void* d_out, int out_size, void* d_ws, size_t ws_size,
                              hipStream_t stream)
{
  (void)in_sizes; (void)n_in; (void)out_size;
  const float* x1     = (const float*)d_in[0];
  const float* x2     = (const float*)d_in[1];
  const float* conv_w = (const float*)d_in[2];
  const float* conv_b = (const float*)d_in[3];
  const float* bn_g   = (const float*)d_in[4];
  const float* bn_b   = (const float*)d_in[5];
  const float* bn_m   = (const float*)d_in[6];
  const float* bn_v   = (const float*)d_in[7];
  const float* ln0_g  = (const float*)d_in[8];
  const float* ln0_b  = (const float*)d_in[9];
  const float* n1_g   = (const float*)d_in[10];
  const float* n1_b   = (const float*)d_in[11];
  const float* qkv_w  = (const float*)d_in[12];
  const float* lepe_w = (const float*)d_in[13];
  const float* lepe_b = (const float*)d_in[14];
  const float* proj_w = (const float*)d_in[15];
  const float* proj_b = (const float*)d_in[16];
  const float* n2_g   = (const float*)d_in[17];
  const float* n2_b   = (const float*)d_in[18];
  const float* fc1_w  = (const float*)d_in[19];
  const float* fc1_b  = (const float*)d_in[20];
  const float* fc2_w  = (const float*)d_in[21];
  const float* fc2_b  = (const float*)d_in[22];

  if (ws_size < 121767936ULL){
    hipMemsetAsync(d_out, 0, (size_t)out_size*4, stream);
    return;
  }

  // ---- workspace layout (NO aliased in-place read/write anywhere) ----
  char* ws = (char*)d_ws;
  ushort* Xin  = (ushort*)ws;
  ushort* QKVb = (ushort*)ws;
  ushort* H1b  = (ushort*)ws;
  ushort* ATTb = (ushort*)(ws + 50331648);
  float*  T    = (float*)(ws + 67108864);
  ushort* Xb   = (ushort*)(ws + 100663296);
  size_t off = 117440512;
  ushort* Wc   = (ushort*)(ws + off); off += 1179648;
  ushort* Wq   = (ushort*)(ws + off); off += 786432;
  ushort* Wp   = (ushort*)(ws + off); off += 262144;
  ushort* W1   = (ushort*)(ws + off); off += 1048576;
  ushort* W2   = (ushort*)(ws + off); off += 1048576;
  float*  scv  = (float*)(ws + off);  off += 1024;
  float*  shv  = (float*)(ws + off);  off += 1024;

  hipMemsetAsync(Xin, 0, (size_t)8*66*66*256*2, stream);
  repack_in_k<<<dim3(64,8), 256, 0, stream>>>(x1, x2, Xin);
  repack_convw_k<<<576, 256, 0, stream>>>(conv_w, Wc);
  for (int i=0;i<2;i++){
    transpose_w_k<<<512,256,0,stream>>>(qkv_w + (long)i*196608, Wq + (long)i*196608, 256, 768);
    transpose_w_k<<<128,256,0,stream>>>(proj_w + (long)i*65536, Wp + (long)i*65536, 256, 256);
    transpose_w_k<<<512,256,0,stream>>>(fc1_w + (long)i*262144, W1 + (long)i*262144, 256, 1024);
    transpose_w_k<<<512,256,0,stream>>>(fc2_w + (long)i*262144, W2 + (long)i*262144, 1024, 256);
  }
  bnprep_k<<<1,256,0,stream>>>(conv_b, bn_g, bn_b, bn_m, bn_v, scv, shv);

  // fused conv+BN+LN0+n1(layer0): -> T (f32 residual base), Xb (bf16 LN'd input to qkv)
  gemm_f<0><<<512,256,0,stream>>>(nullptr, Xin, Wc, nullptr, scv, shv,
                                  T, ln0_g, ln0_b, n1_g, n1_b, Xb, nullptr, 2304);

  for (int i=0;i<2;i++){
    gemm_k<4><<<dim3(256,6),256,0,stream>>>(Xb, Wq + (long)i*196608, nullptr, QKVb, 768, 256);
    attn_k<0><<<dim3(128,8),256,0,stream>>>(QKVb, ATTb, lepe_w, lepe_b, i);
    attn_k<1><<<dim3(128,8),256,0,stream>>>(QKVb, ATTb, lepe_w, lepe_b, i);
    gemm_f<1><<<512,256,0,stream>>>(ATTb, nullptr, Wp + (long)i*65536, proj_b + i*256,
                                    nullptr, nullptr, T, n2_g + i*256, n2_b + i*256,
                                    nullptr, nullptr, Xb, nullptr, 256);
    gemm_k<1><<<dim3(256,8),256,0,stream>>>(Xb, W1 + (long)i*262144, fc1_b + i*1024, H1b, 1024, 256);
    if (i == 0){
      gemm_f<1><<<512,256,0,stream>>>(H1b, nullptr, W2, fc2_b,
                                      nullptr, nullptr, T, n1_g + 256, n1_b + 256,
                                      nullptr, nullptr, Xb, nullptr, 1024);
    } else {
      gemm_f<3><<<512,256,0,stream>>>(H1b, nullptr, W2 + 262144, fc2_b + 256,
                                      nullptr, nullptr, T, nullptr, nullptr,
                                      nullptr, nullptr, nullptr, (float*)d_out, 1024);
    }
  }
}